// Round 24
// baseline (229.987 us; speedup 1.0000x reference)
//
#include <hip/hip_runtime.h>
#include <math.h>

typedef __attribute__((ext_vector_type(8))) short short8v;   // 8 bf16 (4 VGPR)
typedef __attribute__((ext_vector_type(4))) float f32x4;
typedef __attribute__((ext_vector_type(2))) float f32x2;

// ---------------- helpers ----------------
__device__ __forceinline__ unsigned short f2bf(float f) {
    union { float f; unsigned int u; } v; v.f = f;
    unsigned int r = v.u + 0x7FFFu + ((v.u >> 16) & 1u);
    return (unsigned short)(r >> 16);
}
__device__ __forceinline__ float bflo(unsigned int v) {
    union { unsigned int u; float f; } x; x.u = v << 16; return x.f;
}
__device__ __forceinline__ float bfhi(unsigned int v) {
    union { unsigned int u; float f; } x; x.u = v & 0xFFFF0000u; return x.f;
}
__device__ __forceinline__ unsigned char f2fp8(float f) {
    return (unsigned char)(__builtin_amdgcn_cvt_pk_fp8_f32(f, f, 0, false) & 0xFF);
}
__device__ __forceinline__ unsigned pkrtz(float a, float b) {
    unsigned d;
    asm("v_cvt_pkrtz_f16_f32 %0, %1, %2" : "=v"(d) : "v"(a), "v"(b));
    return d;
}
__device__ __forceinline__ float fdot2a(unsigned a, unsigned b, float c) {
    float d;
    asm("v_dot2_f32_f16 %0, %1, %2, %3" : "=v"(d) : "v"(a), "v"(b), "v"(c));
    return d;
}
__device__ __forceinline__ unsigned pk_fma_f16(unsigned a, unsigned b, unsigned c) {
    unsigned d;
    asm("v_pk_fma_f16 %0, %1, %2, %3" : "=v"(d) : "v"(a), "v"(b), "v"(c));
    return d;
}
__device__ __forceinline__ unsigned pk_max0_f16(unsigned a, unsigned z) {
    unsigned d;
    asm("v_pk_max_f16 %0, %1, %2" : "=v"(d) : "v"(a), "v"(z));
    return d;
}

// ---------------- prep: weight pack (384 blocks) + dst histogram (rest) ----------------
__global__ __launch_bounds__(256) void prep_kernel(const float* __restrict__ s0,
                                                   const float* __restrict__ s1,
                                                   const float* __restrict__ s2,
                                                   const float* __restrict__ s3,
                                                   const float* __restrict__ s4,
                                                   const float* __restrict__ s5,
                                                   unsigned short* __restrict__ Wp,
                                                   const int* __restrict__ dst,
                                                   int* __restrict__ deg, int E) {
    int b = blockIdx.x;
    if (b < 384) {
        int which = b >> 6;
        const float* W = (which == 0) ? s0 : (which == 1) ? s1 : (which == 2) ? s2
                       : (which == 3) ? s3 : (which == 4) ? s4 : s5;
        int t = (b & 63) * 256 + threadIdx.x;
        int j = t & 7, l = (t >> 3) & 63, ct = (t >> 9) & 7, ks = t >> 12;
        int k = ks * 32 + (l >> 4) * 8 + j;
        int n = ct * 16 + (l & 15);
        Wp[which * 16384 + t] = f2bf(W[k * 128 + n]);
    } else {
        int e = (b - 384) * 256 + threadIdx.x;
        if (e < E) atomicAdd(&deg[dst[e]], 1);
    }
}

// ---------------- scan stage 1 ----------------
__global__ __launch_bounds__(256) void scan1_kernel(const int* __restrict__ deg,
                                                    int* __restrict__ rp,
                                                    int* __restrict__ bsum, int N) {
    const int lane = threadIdx.x & 63, wid = threadIdx.x >> 6;
    int i = blockIdx.x * 256 + threadIdx.x;
    int v = (i < N) ? deg[i] : 0;
    int val = v;
#pragma unroll
    for (int off = 1; off < 64; off <<= 1) {
        int t = __shfl_up(val, off, 64);
        if (lane >= off) val += t;
    }
    __shared__ int ws[4];
    if (lane == 63) ws[wid] = val;
    __syncthreads();
    int pre = 0;
#pragma unroll
    for (int w = 0; w < 4; ++w) pre += (w < wid) ? ws[w] : 0;
    int incl = pre + val;
    if (i < N) rp[i] = incl - v;
    if (threadIdx.x == 255) bsum[blockIdx.x] = incl;
}

// ---------------- scan stage 2+3 + graph bounds, fused ----------------
__global__ __launch_bounds__(256) void scan23_kernel(int* __restrict__ rp,
                                                     const int* __restrict__ bsum,
                                                     const int* __restrict__ batch,
                                                     int* __restrict__ gstart,
                                                     int* __restrict__ gend,
                                                     int N, int E) {
    const int lane = threadIdx.x & 63, wid = threadIdx.x >> 6;
    const int b = blockIdx.x;
    int v = ((int)threadIdx.x < b) ? bsum[threadIdx.x] : 0;
#pragma unroll
    for (int m = 32; m >= 1; m >>= 1) v += __shfl_xor(v, m, 64);
    __shared__ int ws[4];
    if (lane == 0) ws[wid] = v;
    __syncthreads();
    int offset = ws[0] + ws[1] + ws[2] + ws[3];
    int i = b * 256 + threadIdx.x;
    if (i < N) {
        rp[i] += offset;
        int bb = batch[i];
        if (i == 0 || batch[i - 1] != bb) gstart[bb] = i;
        if (i == N - 1 || batch[i + 1] != bb) gend[bb] = i + 1;
    }
    if (b == 0 && threadIdx.x == 0) rp[N] = E;
}

// ---------------- FUSED: scatter (latency-bound) || linpq conv1 (compute-bound) ----------------
__global__ __launch_bounds__(256) void linpq_scat_kernel(
    const float* __restrict__ Av,
    const unsigned short* __restrict__ WpL, const float* __restrict__ bias,
    const unsigned short* __restrict__ WpP, const unsigned short* __restrict__ WpQ,
    const float* __restrict__ ab1,
    unsigned short* __restrict__ Dbf, unsigned char* __restrict__ Vf8,
    unsigned char* __restrict__ Pf8, unsigned char* __restrict__ Qf8, int M, int LB,
    const int* __restrict__ src, const int* __restrict__ dst,
    const float* __restrict__ aux, const int* __restrict__ rowptr,
    int* __restrict__ cursor, uint2* __restrict__ er, int E) {
    __shared__ char smem[32 * 136 * 2 + 32 * 128];   // 12800 B
    unsigned short (*lds)[136] = (unsigned short(*)[136])smem;
    unsigned char (*ldsV)[128] = (unsigned char(*)[128])(smem + 8704);
    unsigned char (*ldsP)[128] = (unsigned char(*)[128])smem;           // aliases lds
    unsigned char (*ldsQ)[128] = (unsigned char(*)[128])(smem + 4096);  // aliases lds

    const int b = blockIdx.x;
    int bi;
    bool isScat;
    if (b < 2 * LB) { isScat = ((b & 1) == 0); bi = b >> 1; }
    else            { isScat = true;           bi = LB + (b - 2 * LB); }

    if (isScat) {
        int e = bi * 256 + (int)threadIdx.x;
        if (e < E) {
            int d = dst[e];
            int pos = rowptr[d] + atomicAdd(&cursor[d], 1);
            float2 a = *(const float2*)(aux + 2 * e);
            uint2 r;
            r.x = (unsigned)src[e] | ((unsigned)d << 16);
            r.y = (unsigned)f2bf(a.x) | ((unsigned)f2bf(a.y) << 16);
            er[pos] = r;
        }
        return;
    }

    const int l = threadIdx.x & 63, w = threadIdx.x >> 6;
    const int tile = w >> 1, ch = w & 1;
    const int rowb = bi * 32;
    const int rowbase = rowb + tile * 16;
    const int r = rowbase + (l & 15);
    const int kc = (l >> 4) * 8;

    short8v afr[4];
    if (r < M) {
        const float* ap = Av + (size_t)r * 128 + kc;
#pragma unroll
        for (int ks = 0; ks < 4; ++ks) {
            float4 x0 = *(const float4*)(ap + ks * 32);
            float4 x1 = *(const float4*)(ap + ks * 32 + 4);
            unsigned short u[8] = {f2bf(x0.x), f2bf(x0.y), f2bf(x0.z), f2bf(x0.w),
                                   f2bf(x1.x), f2bf(x1.y), f2bf(x1.z), f2bf(x1.w)};
            afr[ks] = *(short8v*)u;
        }
    } else {
#pragma unroll
        for (int ks = 0; ks < 4; ++ks)
#pragma unroll
            for (int j = 0; j < 8; ++j) afr[ks][j] = 0;
    }

    f32x4 acc[4];
#pragma unroll
    for (int c = 0; c < 4; ++c)
#pragma unroll
        for (int j = 0; j < 4; ++j) acc[c][j] = 0.f;

    const short8v* wl = (const short8v*)WpL;
#pragma unroll
    for (int ks = 0; ks < 4; ++ks)
#pragma unroll
        for (int c = 0; c < 4; ++c)
            acc[c] = __builtin_amdgcn_mfma_f32_16x16x32_bf16(
                afr[ks], wl[(ks * 8 + ch * 4 + c) * 64 + l], acc[c], 0, 0, 0);

    const int lrb = tile * 16 + (l >> 4) * 4;
#pragma unroll
    for (int c = 0; c < 4; ++c) {
        int col = (ch * 4 + c) * 16 + (l & 15);
        float bv = bias[col];
#pragma unroll
        for (int j = 0; j < 4; ++j) {
            float v = acc[c][j] + bv;
            lds[lrb + j][col] = f2bf(v);
            ldsV[lrb + j][col] = f2fp8(v);
        }
    }
    __syncthreads();

    {
        int r2 = threadIdx.x >> 3, q2 = threadIdx.x & 7;  // 8 thr/row
        if (rowb + r2 < M) {
            *(uint4*)(Dbf + (size_t)(rowb + r2) * 128 + q2 * 16) =
                *(uint4*)&lds[r2][q2 * 16];
            *(uint4*)(Dbf + (size_t)(rowb + r2) * 128 + q2 * 16 + 8) =
                *(uint4*)&lds[r2][q2 * 16 + 8];
            *(uint4*)(Vf8 + (size_t)(rowb + r2) * 128 + q2 * 16) =
                *(uint4*)&ldsV[r2][q2 * 16];
        }
    }

    short8v xfr[4];
#pragma unroll
    for (int ks = 0; ks < 4; ++ks)
        xfr[ks] = *(const short8v*)&lds[tile * 16 + (l & 15)][kc + ks * 32];
    __syncthreads();   // close all reads of lds before aliased P/Q writes

    f32x4 accP[4], accQ[4];
#pragma unroll
    for (int c = 0; c < 4; ++c)
#pragma unroll
        for (int j = 0; j < 4; ++j) { accP[c][j] = 0.f; accQ[c][j] = 0.f; }

    const short8v* wp = (const short8v*)WpP;
    const short8v* wq = (const short8v*)WpQ;
#pragma unroll
    for (int ks = 0; ks < 4; ++ks)
#pragma unroll
        for (int c = 0; c < 4; ++c) {
            accP[c] = __builtin_amdgcn_mfma_f32_16x16x32_bf16(
                xfr[ks], wp[(ks * 8 + ch * 4 + c) * 64 + l], accP[c], 0, 0, 0);
            accQ[c] = __builtin_amdgcn_mfma_f32_16x16x32_bf16(
                xfr[ks], wq[(ks * 8 + ch * 4 + c) * 64 + l], accQ[c], 0, 0, 0);
        }

#pragma unroll
    for (int c = 0; c < 4; ++c) {
        int col = (ch * 4 + c) * 16 + (l & 15);
        float b1v = ab1[col];
#pragma unroll
        for (int j = 0; j < 4; ++j) {
            ldsP[lrb + j][col] = f2fp8(accP[c][j]);
            ldsQ[lrb + j][col] = f2fp8(accQ[c][j] + b1v);
        }
    }
    __syncthreads();
    {
        int r2 = threadIdx.x >> 3, q2 = threadIdx.x & 7;
        if (rowb + r2 < M) {
            *(uint4*)(Pf8 + (size_t)(rowb + r2) * 128 + q2 * 16) =
                *(uint4*)&ldsP[r2][q2 * 16];
            *(uint4*)(Qf8 + (size_t)(rowb + r2) * 128 + q2 * 16) =
                *(uint4*)&ldsQ[r2][q2 * 16];
        }
    }
}

// ---------------- two-phase MFMA GEMM (conv2, bf16 input), same LDS aliasing ----------------
__global__ __launch_bounds__(256) void linpq_kernel(const unsigned short* __restrict__ Av,
                                                    const unsigned short* __restrict__ WpL,
                                                    const float* __restrict__ bias,
                                                    const unsigned short* __restrict__ WpP,
                                                    const unsigned short* __restrict__ WpQ,
                                                    const float* __restrict__ ab1,
                                                    unsigned short* __restrict__ Dbf,
                                                    unsigned char* __restrict__ Vf8,
                                                    unsigned char* __restrict__ Pf8,
                                                    unsigned char* __restrict__ Qf8, int M) {
    __shared__ char smem[32 * 136 * 2 + 32 * 128];   // 12800 B
    unsigned short (*lds)[136] = (unsigned short(*)[136])smem;
    unsigned char (*ldsV)[128] = (unsigned char(*)[128])(smem + 8704);
    unsigned char (*ldsP)[128] = (unsigned char(*)[128])smem;
    unsigned char (*ldsQ)[128] = (unsigned char(*)[128])(smem + 4096);

    const int l = threadIdx.x & 63, w = threadIdx.x >> 6;
    const int tile = w >> 1, ch = w & 1;
    const int rowb = blockIdx.x * 32;
    const int rowbase = rowb + tile * 16;
    const int r = rowbase + (l & 15);
    const int kc = (l >> 4) * 8;

    short8v afr[4];
    if (r < M) {
        const unsigned short* ap = Av + (size_t)r * 128 + kc;
#pragma unroll
        for (int ks = 0; ks < 4; ++ks)
            afr[ks] = *(const short8v*)(ap + ks * 32);
    } else {
#pragma unroll
        for (int ks = 0; ks < 4; ++ks)
#pragma unroll
            for (int j = 0; j < 8; ++j) afr[ks][j] = 0;
    }

    f32x4 acc[4];
#pragma unroll
    for (int c = 0; c < 4; ++c)
#pragma unroll
        for (int j = 0; j < 4; ++j) acc[c][j] = 0.f;

    const short8v* wl = (const short8v*)WpL;
#pragma unroll
    for (int ks = 0; ks < 4; ++ks)
#pragma unroll
        for (int c = 0; c < 4; ++c)
            acc[c] = __builtin_amdgcn_mfma_f32_16x16x32_bf16(
                afr[ks], wl[(ks * 8 + ch * 4 + c) * 64 + l], acc[c], 0, 0, 0);

    const int lrb = tile * 16 + (l >> 4) * 4;
#pragma unroll
    for (int c = 0; c < 4; ++c) {
        int col = (ch * 4 + c) * 16 + (l & 15);
        float bv = bias[col];
#pragma unroll
        for (int j = 0; j < 4; ++j) {
            float v = acc[c][j] + bv;
            lds[lrb + j][col] = f2bf(v);
            ldsV[lrb + j][col] = f2fp8(v);
        }
    }
    __syncthreads();

    {
        int r2 = threadIdx.x >> 3, q2 = threadIdx.x & 7;
        if (rowb + r2 < M) {
            *(uint4*)(Dbf + (size_t)(rowb + r2) * 128 + q2 * 16) =
                *(uint4*)&lds[r2][q2 * 16];
            *(uint4*)(Dbf + (size_t)(rowb + r2) * 128 + q2 * 16 + 8) =
                *(uint4*)&lds[r2][q2 * 16 + 8];
            *(uint4*)(Vf8 + (size_t)(rowb + r2) * 128 + q2 * 16) =
                *(uint4*)&ldsV[r2][q2 * 16];
        }
    }

    short8v xfr[4];
#pragma unroll
    for (int ks = 0; ks < 4; ++ks)
        xfr[ks] = *(const short8v*)&lds[tile * 16 + (l & 15)][kc + ks * 32];
    __syncthreads();   // close all reads of lds before aliased P/Q writes

    f32x4 accP[4], accQ[4];
#pragma unroll
    for (int c = 0; c < 4; ++c)
#pragma unroll
        for (int j = 0; j < 4; ++j) { accP[c][j] = 0.f; accQ[c][j] = 0.f; }

    const short8v* wp = (const short8v*)WpP;
    const short8v* wq = (const short8v*)WpQ;
#pragma unroll
    for (int ks = 0; ks < 4; ++ks)
#pragma unroll
        for (int c = 0; c < 4; ++c) {
            accP[c] = __builtin_amdgcn_mfma_f32_16x16x32_bf16(
                xfr[ks], wp[(ks * 8 + ch * 4 + c) * 64 + l], accP[c], 0, 0, 0);
            accQ[c] = __builtin_amdgcn_mfma_f32_16x16x32_bf16(
                xfr[ks], wq[(ks * 8 + ch * 4 + c) * 64 + l], accQ[c], 0, 0, 0);
        }

#pragma unroll
    for (int c = 0; c < 4; ++c) {
        int col = (ch * 4 + c) * 16 + (l & 15);
        float b1v = ab1[col];
#pragma unroll
        for (int j = 0; j < 4; ++j) {
            ldsP[lrb + j][col] = f2fp8(accP[c][j]);
            ldsQ[lrb + j][col] = f2fp8(accQ[c][j] + b1v);
        }
    }
    __syncthreads();
    {
        int r2 = threadIdx.x >> 3, q2 = threadIdx.x & 7;
        if (rowb + r2 < M) {
            *(uint4*)(Pf8 + (size_t)(rowb + r2) * 128 + q2 * 16) =
                *(uint4*)&ldsP[r2][q2 * 16];
            *(uint4*)(Qf8 + (size_t)(rowb + r2) * 128 + q2 * 16) =
                *(uint4*)&ldsQ[r2][q2 * 16];
        }
    }
}

// ---------------- edge-parallel logits: 2 lanes/edge, 64 ch/lane, packed-f16 math ----------------
__global__ __launch_bounds__(256, 4) void attn_edge_kernel(
    const unsigned char* __restrict__ Pf8, const unsigned char* __restrict__ Qf8,
    const uint2* __restrict__ er,
    const float* __restrict__ wa0, const float* __restrict__ wa1,
    const float* __restrict__ lng, const float* __restrict__ lnb,
    const float* __restrict__ aw2, const float* __restrict__ ab2,
    float* __restrict__ wt, int E) {
    __shared__ float lwf[256];      // [arr:2][c:16][par:2][4] f32 (wa0, wa1)
    __shared__ unsigned lwh[192];   // [arr:3][c:16][par:2][pair:2] f16x2 (lng, lnb, aw2)
    {
        int idx = threadIdx.x;
        int arr = idx >> 7, rem = idx & 127;
        int par = rem >> 6, c = (rem >> 2) & 15, e = rem & 3;
        const float* sp = arr ? wa1 : wa0;
        lwf[(((arr * 16 + c) << 1) + par) * 4 + e] = sp[rem];
        if (idx < 192) {
            int a2 = idx >> 6, rem2 = idx & 63;
            int p2 = rem2 >> 5;
            int c2 = (rem2 >> 1) & 15;
            int pr = rem2 & 1;
            int chn = p2 * 64 + c2 * 4 + pr * 2;
            const float* s2 = (a2 == 0) ? lng : (a2 == 1) ? lnb : aw2;
            lwh[(((a2 * 16 + c2) << 1) + p2) * 2 + pr] = pkrtz(s2[chn], s2[chn + 1]);
        }
    }
    __syncthreads();
    const int slot = blockIdx.x * 128 + ((int)threadIdx.x >> 1);
    if (slot >= E) return;
    const int par = threadIdx.x & 1;
    const unsigned one2 = 0x3C003C00u;
    const unsigned zero2 = 0u;
    const int co = par << 6;

    uint2 ev = er[slot];
    const int sn = (int)(ev.x & 0xFFFFu);
    const int dn = (int)(ev.x >> 16);
    const float ax = bflo(ev.y), ay = bfhi(ev.y);

    const uint4* prow = (const uint4*)(Pf8 + (size_t)sn * 128 + co);
    const uint4* qrow = (const uint4*)(Qf8 + (size_t)dn * 128 + co);

    float r1 = 0.f, r2 = 0.f;
    unsigned tp[32];

#pragma unroll
    for (int g = 0; g < 4; ++g) {
        uint4 pv = prow[g];
        uint4 qv = qrow[g];
        unsigned pwa[4] = {pv.x, pv.y, pv.z, pv.w};
        unsigned qwa[4] = {qv.x, qv.y, qv.z, qv.w};
#pragma unroll
        for (int cc = 0; cc < 4; ++cc) {
            const int c = g * 4 + cc;
            f32x2 plo = __builtin_amdgcn_cvt_pk_f32_fp8((int)pwa[cc], false);
            f32x2 phi = __builtin_amdgcn_cvt_pk_f32_fp8((int)pwa[cc], true);
            f32x2 qlo = __builtin_amdgcn_cvt_pk_f32_fp8((int)qwa[cc], false);
            f32x2 qhi = __builtin_amdgcn_cvt_pk_f32_fp8((int)qwa[cc], true);
            float4 w0v = *(const float4*)&lwf[((c << 1) + par) * 4];
            float4 w1v = *(const float4*)&lwf[(((16 + c) << 1) + par) * 4];
            float t0 = plo[0] + qlo[0] + ax * w0v.x + ay * w1v.x;
            float t1 = plo[1] + qlo[1] + ax * w0v.y + ay * w1v.y;
            float t2 = phi[0] + qhi[0] + ax * w0v.z + ay * w1v.z;
            float t3 = phi[1] + qhi[1] + ax * w0v.w + ay * w1v.w;
            unsigned p0 = pkrtz(t0, t1);
            unsigned p1 = pkrtz(t2, t3);
            tp[2 * c] = p0;
            tp[2 * c + 1] = p1;
            r1 = fdot2a(p0, one2, r1);
            r1 = fdot2a(p1, one2, r1);
            r2 = fdot2a(p0, p0, r2);
            r2 = fdot2a(p1, p1, r2);
        }
    }
    r1 += __shfl_xor(r1, 1, 64);
    r2 += __shfl_xor(r2, 1, 64);
    float mean = r1 * (1.f / 128.f);
    float rstd = rsqrtf(r2 * (1.f / 128.f) - mean * mean + 1e-5f);
    float mr = mean * rstd;
    unsigned rstd2 = pkrtz(rstd, rstd);
    unsigned nmr2 = pkrtz(-mr, -mr);

    float dot = 0.f;
#pragma unroll
    for (int c = 0; c < 16; ++c) {
        unsigned base = (unsigned)(((c << 1) + par) * 2);
        uint2 gg = *(const uint2*)&lwh[base];
        uint2 ll = *(const uint2*)&lwh[64 + base];
        uint2 ww = *(const uint2*)&lwh[128 + base];
        unsigned u0 = pk_fma_f16(tp[2 * c], rstd2, nmr2);
        u0 = pk_fma_f16(u0, gg.x, ll.x);
        u0 = pk_max0_f16(u0, zero2);
        dot = fdot2a(u0, ww.x, dot);
        unsigned u1 = pk_fma_f16(tp[2 * c + 1], rstd2, nmr2);
        u1 = pk_fma_f16(u1, gg.y, ll.y);
        u1 = pk_max0_f16(u1, zero2);
        dot = fdot2a(u1, ww.y, dot);
    }
    dot += __shfl_xor(dot, 1, 64);
    if (par == 0) wt[slot] = __expf(dot + ab2[0]);
}

// ---------------- aggregation: 8 lanes/node, 16 ch/lane; 4-deep prefetch ----------------
template <int MODE>
__global__ __launch_bounds__(256) void aggr_kernel(
    const unsigned short* __restrict__ xlbf, const unsigned char* __restrict__ Vf8,
    const float* __restrict__ wt,
    const uint2* __restrict__ er, const int* __restrict__ rowptr,
    const float* __restrict__ g, const float* __restrict__ b,
    void* __restrict__ out, int N) {
    const int lane8 = threadIdx.x & 7;
    const int v = blockIdx.x * 32 + ((int)threadIdx.x >> 3);
    if (v >= N) return;
    const int jb = lane8 * 16;

    const int s0 = rowptr[v], s1e = rowptr[v + 1];
    const int deg = s1e - s0;
    float acc[16];
#pragma unroll
    for (int k = 0; k < 16; ++k) acc[k] = 0.f;
    float wsum = 0.f;

    uint4 pv[4];
    float pw[4];
#pragma unroll
    for (int k = 0; k < 4; ++k) { pv[k] = make_uint4(0, 0, 0, 0); pw[k] = 0.f; }
#define GATH2(idx, VV, WW)                                                       \
    if ((idx) < s1e) {                                                           \
        int sn_ = (int)(er[idx].x & 0xFFFFu);                                    \
        VV = *(const uint4*)(Vf8 + (size_t)sn_ * 128 + jb);                      \
        WW = wt[idx];                                                            \
    }
    GATH2(s0 + 0, pv[0], pw[0])
    GATH2(s0 + 1, pv[1], pw[1])
    GATH2(s0 + 2, pv[2], pw[2])
    GATH2(s0 + 3, pv[3], pw[3])

    for (int i = s0; i < s1e; i += 4) {
        uint4 c0 = pv[0], c1 = pv[1], c2 = pv[2], c3 = pv[3];
        float u0 = pw[0];
        float u1 = (i + 1 < s1e) ? pw[1] : 0.f;
        float u2 = (i + 2 < s1e) ? pw[2] : 0.f;
        float u3 = (i + 3 < s1e) ? pw[3] : 0.f;
        GATH2(i + 4, pv[0], pw[0])
        GATH2(i + 5, pv[1], pw[1])
        GATH2(i + 6, pv[2], pw[2])
        GATH2(i + 7, pv[3], pw[3])
        wsum += (u0 + u1) + (u2 + u3);
        unsigned d0[4] = {c0.x, c0.y, c0.z, c0.w};
        unsigned d1[4] = {c1.x, c1.y, c1.z, c1.w};
        unsigned d2[4] = {c2.x, c2.y, c2.z, c2.w};
        unsigned d3[4] = {c3.x, c3.y, c3.z, c3.w};
#pragma unroll
        for (int k = 0; k < 4; ++k) {
            f32x2 a0 = __builtin_amdgcn_cvt_pk_f32_fp8((int)d0[k], false);
            f32x2 a1 = __builtin_amdgcn_cvt_pk_f32_fp8((int)d0[k], true);
            f32x2 b0 = __builtin_amdgcn_cvt_pk_f32_fp8((int)d1[k], false);
            f32x2 b1 = __builtin_amdgcn_cvt_pk_f32_fp8((int)d1[k], true);
            f32x2 e0 = __builtin_amdgcn_cvt_pk_f32_fp8((int)d2[k], false);
            f32x2 e1 = __builtin_amdgcn_cvt_pk_f32_fp8((int)d2[k], true);
            f32x2 f0 = __builtin_amdgcn_cvt_pk_f32_fp8((int)d3[k], false);
            f32x2 f1 = __builtin_amdgcn_cvt_pk_f32_fp8((int)d3[k], true);
            acc[4 * k + 0] += (u0 * a0[0] + u1 * b0[0]) + (u2 * e0[0] + u3 * f0[0]);
            acc[4 * k + 1] += (u0 * a0[1] + u1 * b0[1]) + (u2 * e0[1] + u3 * f0[1]);
            acc[4 * k + 2] += (u0 * a1[0] + u1 * b1[0]) + (u2 * e1[0] + u3 * f1[0]);
            acc[4 * k + 3] += (u0 * a1[1] + u1 * b1[1]) + (u2 * e1[1] + u3 * f1[1]);
        }
    }
#undef GATH2

    const float ns = (deg > 0) ? 1.f / (wsum * (float)deg) : 0.f;
    float o[16];
    const unsigned short* xp = xlbf + (size_t)v * 128 + jb;
    uint4 xa = *(const uint4*)xp;
    uint4 xb = *(const uint4*)(xp + 8);
    unsigned xw[8] = {xa.x, xa.y, xa.z, xa.w, xb.x, xb.y, xb.z, xb.w};
#pragma unroll
    for (int k = 0; k < 8; ++k) {
        o[2 * k] = bflo(xw[k]) + acc[2 * k] * ns;
        o[2 * k + 1] = bfhi(xw[k]) + acc[2 * k + 1] * ns;
    }

    if (MODE == 0) {
        unsigned short* op = (unsigned short*)out + (size_t)v * 128 + jb;
        unsigned opk[8];
#pragma unroll
        for (int k = 0; k < 8; ++k)
            opk[k] = (unsigned)f2bf(fmaxf(o[2 * k], 0.f)) |
                     ((unsigned)f2bf(fmaxf(o[2 * k + 1], 0.f)) << 16);
        *(uint4*)op = make_uint4(opk[0], opk[1], opk[2], opk[3]);
        *(uint4*)(op + 8) = make_uint4(opk[4], opk[5], opk[6], opk[7]);
    } else {
        float r1 = 0.f, r2 = 0.f;
#pragma unroll
        for (int k = 0; k < 16; ++k) { r1 += o[k]; r2 = fmaf(o[k], o[k], r2); }
#pragma unroll
        for (int mk = 4; mk >= 1; mk >>= 1) {
            r1 += __shfl_xor(r1, mk, 64);
            r2 += __shfl_xor(r2, mk, 64);
        }
        float mean = r1 * (1.f / 128.f);
        float rstd = rsqrtf(r2 * (1.f / 128.f) - mean * mean + 1e-5f);
        float mr = mean * rstd;
        float* op = (float*)out + (size_t)v * 128 + jb;
#pragma unroll
        for (int k4 = 0; k4 < 4; ++k4) {
            float4 gv = *(const float4*)(g + jb + 4 * k4);
            float4 bv = *(const float4*)(b + jb + 4 * k4);
            float4 r;
            r.x = fmaf(fmaf(o[4 * k4 + 0], rstd, -mr), gv.x, bv.x);
            r.y = fmaf(fmaf(o[4 * k4 + 1], rstd, -mr), gv.y, bv.y);
            r.z = fmaf(fmaf(o[4 * k4 + 2], rstd, -mr), gv.z, bv.z);
            r.w = fmaf(fmaf(o[4 * k4 + 3], rstd, -mr), gv.w, bv.w);
            *(float4*)(op + 4 * k4) = r;
        }
    }
}

// ---------------- pool stage 1: per-(graph, slice) partial max ----------------
__global__ __launch_bounds__(128) void pool1_kernel(const float* __restrict__ h,
                                                    const int* __restrict__ gstart,
                                                    const int* __restrict__ gend,
                                                    float* __restrict__ part) {
    int gph = blockIdx.x >> 4;
    int sl = blockIdx.x & 15;
    int col = threadIdx.x;
    int s = gstart[gph], e = gend[gph];
    float m = -INFINITY;
    for (int r = s + sl; r < e; r += 16) m = fmaxf(m, h[(size_t)r * 128 + col]);
    part[(size_t)blockIdx.x * 128 + col] = m;
}

// ---------------- classifier head (folds pool stage 2) ----------------
__global__ __launch_bounds__(128) void cls_kernel(const float* __restrict__ part,
                                                  const float* __restrict__ cw,
                                                  const float* __restrict__ cb,
                                                  float* __restrict__ out) {
    int gph = blockIdx.x, c = threadIdx.x;
    float m = -INFINITY;
#pragma unroll
    for (int sl = 0; sl < 16; ++sl) m = fmaxf(m, part[(size_t)(gph * 16 + sl) * 128 + c]);
    __shared__ float f[128];
    f[c] = m;
    __syncthreads();
    float acc = cb[c];
#pragma unroll 8
    for (int k = 0; k < 128; ++k) acc += f[k] * cw[k * 128 + c];
    out[gph * 128 + c] = acc;
}

// ---------------- launch ----------------
extern "C" void kernel_launch(void* const* d_in, const int* in_sizes, int n_in,
                              void* d_out, int out_size, void* d_ws, size_t ws_size,
                              hipStream_t stream) {
    const float* x      = (const float*)d_in[0];
    const int*   ei     = (const int*)d_in[1];
    const float* aux    = (const float*)d_in[2];
    const int*   batch  = (const int*)d_in[3];
    const float* w_lin1 = (const float*)d_in[4];
    const float* b_lin1 = (const float*)d_in[5];
    const float* aw1_1  = (const float*)d_in[6];
    const float* ab1_1  = (const float*)d_in[7];
    const float* lng1   = (const float*)d_in[8];
    const float* lnb1   = (const float*)d_in[9];
    const float* aw2_1  = (const float*)d_in[10];
    const float* ab2_1  = (const float*)d_in[11];
    const float* w_lin2 = (const float*)d_in[12];
    const float* b_lin2 = (const float*)d_in[13];
    const float* aw1_2  = (const float*)d_in[14];
    const float* ab1_2  = (const float*)d_in[15];
    const float* lng2   = (const float*)d_in[16];
    const float* lnb2   = (const float*)d_in[17];
    const float* aw2_2  = (const float*)d_in[18];
    const float* ab2_2  = (const float*)d_in[19];
    const float* cls_w  = (const float*)d_in[20];
    const float* cls_b  = (const float*)d_in[21];
    const float* norm_g = (const float*)d_in[22];
    const float* norm_b = (const float*)d_in[23];

    const int N = in_sizes[0] / 128;
    const int E = in_sizes[2] / 2;
    const int G = 64;
    const int* src = ei;
    const int* dst = ei + E;

    // workspace layout: 16B-aligned buffers first
    char* wsp = (char*)d_ws;
    unsigned short* xlbf  = (unsigned short*)wsp;   wsp += (size_t)N * 128 * 2;
    unsigned short* h1bf  = (unsigned short*)wsp;   wsp += (size_t)N * 128 * 2;
    unsigned char*  Pf8   = (unsigned char*)wsp;    wsp += (size_t)N * 128;
    unsigned char*  Qf8   = (unsigned char*)wsp;    wsp += (size_t)N * 128;
    unsigned char*  Vf8   = (unsigned char*)wsp;    wsp += (size_t)N * 128;
    unsigned short* wpack = (unsigned short*)wsp;   wsp += 6 * 16384 * 2;
    float*          part  = (float*)wsp;            wsp += (size_t)1024 * 128 * 4;
    uint2*          er    = (uint2*)wsp;            wsp += (size_t)E * 8;
    float*          wt    = (float*)wsp;            wsp += (size_t)E * 4;
    int*            bsum    = (int*)wsp;            wsp += 256 * 4;
    int*            deg     = (int*)wsp;            wsp += (size_t)N * 4;
    int*            cursor  = (int*)wsp;            wsp += (size_t)N * 4;
    int*            rowptr  = (int*)wsp;            wsp += (size_t)(N + 1) * 4;
    int*            gstart  = (int*)wsp;            wsp += (size_t)G * 4;
    int*            gend    = (int*)wsp;            wsp += (size_t)G * 4;

    unsigned short* wp_lin1 = wpack;
    unsigned short* wp_s1   = wpack + 16384;
    unsigned short* wp_d1   = wpack + 2 * 16384;
    unsigned short* wp_lin2 = wpack + 3 * 16384;
    unsigned short* wp_s2   = wpack + 4 * 16384;
    unsigned short* wp_d2   = wpack + 5 * 16384;

    float* hout   = (float*)d_out;
    float* clsout = hout + (size_t)N * 128;

    hipMemsetAsync(deg, 0, (size_t)(2 * N) * sizeof(int), stream);      // deg + cursor
    hipMemsetAsync(gstart, 0, (size_t)(2 * G) * sizeof(int), stream);

    const int eb = (E + 255) / 256;
    const int nb = (N + 255) / 256;
    const int lb = (N + 31) / 32;
    const int atb = (E + 127) / 128;
    const int agb = (N + 31) / 32;

    prep_kernel<<<384 + eb, 256, 0, stream>>>(w_lin1, aw1_1, aw1_1 + 128 * 128,
                                              w_lin2, aw1_2, aw1_2 + 128 * 128,
                                              wpack, dst, deg, E);
    scan1_kernel<<<nb, 256, 0, stream>>>(deg, rowptr, bsum, N);
    scan23_kernel<<<nb, 256, 0, stream>>>(rowptr, bsum, batch, gstart, gend, N, E);

    // ---- conv1 (scatter overlapped with linpq) ----
    linpq_scat_kernel<<<lb + eb, 256, 0, stream>>>(x, wp_lin1, b_lin1, wp_s1, wp_d1,
                                                   ab1_1, xlbf, Vf8, Pf8, Qf8, N, lb,
                                                   src, dst, aux, rowptr, cursor, er, E);
    attn_edge_kernel<<<atb, 256, 0, stream>>>(Pf8, Qf8, er,
                                              aw1_1 + 256 * 128, aw1_1 + 257 * 128,
                                              lng1, lnb1, aw2_1, ab2_1, wt, E);
    aggr_kernel<0><<<agb, 256, 0, stream>>>(xlbf, Vf8, wt, er, rowptr,
                                            nullptr, nullptr, h1bf, N);
    // ---- conv2 ----
    linpq_kernel<<<lb, 256, 0, stream>>>(h1bf, wp_lin2, b_lin2, wp_s2, wp_d2, ab1_2,
                                         xlbf, Vf8, Pf8, Qf8, N);
    attn_edge_kernel<<<atb, 256, 0, stream>>>(Pf8, Qf8, er,
                                              aw1_2 + 256 * 128, aw1_2 + 257 * 128,
                                              lng2, lnb2, aw2_2, ab2_2, wt, E);
    aggr_kernel<1><<<agb, 256, 0, stream>>>(xlbf, Vf8, wt, er, rowptr,
                                            norm_g, norm_b, hout, N);
    // ---- head ----
    pool1_kernel<<<G * 16, 128, 0, stream>>>(hout, gstart, gend, part);
    cls_kernel<<<G, 128, 0, stream>>>(part, cls_w, cls_b, clsout);
}

// Round 25
// 229.774 us; speedup vs baseline: 1.0009x; 1.0009x over previous
//
#include <hip/hip_runtime.h>
#include <math.h>

typedef __attribute__((ext_vector_type(8))) short short8v;   // 8 bf16 (4 VGPR)
typedef __attribute__((ext_vector_type(4))) float f32x4;
typedef __attribute__((ext_vector_type(2))) float f32x2;

// ---------------- helpers ----------------
__device__ __forceinline__ unsigned short f2bf(float f) {
    union { float f; unsigned int u; } v; v.f = f;
    unsigned int r = v.u + 0x7FFFu + ((v.u >> 16) & 1u);
    return (unsigned short)(r >> 16);
}
__device__ __forceinline__ float bflo(unsigned int v) {
    union { unsigned int u; float f; } x; x.u = v << 16; return x.f;
}
__device__ __forceinline__ float bfhi(unsigned int v) {
    union { unsigned int u; float f; } x; x.u = v & 0xFFFF0000u; return x.f;
}
__device__ __forceinline__ unsigned char f2fp8(float f) {
    return (unsigned char)(__builtin_amdgcn_cvt_pk_fp8_f32(f, f, 0, false) & 0xFF);
}
__device__ __forceinline__ unsigned pkrtz(float a, float b) {
    unsigned d;
    asm("v_cvt_pkrtz_f16_f32 %0, %1, %2" : "=v"(d) : "v"(a), "v"(b));
    return d;
}
__device__ __forceinline__ float fdot2a(unsigned a, unsigned b, float c) {
    float d;
    asm("v_dot2_f32_f16 %0, %1, %2, %3" : "=v"(d) : "v"(a), "v"(b), "v"(c));
    return d;
}
__device__ __forceinline__ unsigned pk_fma_f16(unsigned a, unsigned b, unsigned c) {
    unsigned d;
    asm("v_pk_fma_f16 %0, %1, %2, %3" : "=v"(d) : "v"(a), "v"(b), "v"(c));
    return d;
}
__device__ __forceinline__ unsigned pk_max0_f16(unsigned a, unsigned z) {
    unsigned d;
    asm("v_pk_max_f16 %0, %1, %2" : "=v"(d) : "v"(a), "v"(z));
    return d;
}

// ---------------- prep: weight pack (384 blocks) + dst histogram (rest) ----------------
__global__ __launch_bounds__(256) void prep_kernel(const float* __restrict__ s0,
                                                   const float* __restrict__ s1,
                                                   const float* __restrict__ s2,
                                                   const float* __restrict__ s3,
                                                   const float* __restrict__ s4,
                                                   const float* __restrict__ s5,
                                                   unsigned short* __restrict__ Wp,
                                                   const int* __restrict__ dst,
                                                   int* __restrict__ deg, int E) {
    int b = blockIdx.x;
    if (b < 384) {
        int which = b >> 6;
        const float* W = (which == 0) ? s0 : (which == 1) ? s1 : (which == 2) ? s2
                       : (which == 3) ? s3 : (which == 4) ? s4 : s5;
        int t = (b & 63) * 256 + threadIdx.x;
        int j = t & 7, l = (t >> 3) & 63, ct = (t >> 9) & 7, ks = t >> 12;
        int k = ks * 32 + (l >> 4) * 8 + j;
        int n = ct * 16 + (l & 15);
        Wp[which * 16384 + t] = f2bf(W[k * 128 + n]);
    } else {
        int e = (b - 384) * 256 + threadIdx.x;
        if (e < E) atomicAdd(&deg[dst[e]], 1);
    }
}

// ---------------- scan stage 1 ----------------
__global__ __launch_bounds__(256) void scan1_kernel(const int* __restrict__ deg,
                                                    int* __restrict__ rp,
                                                    int* __restrict__ bsum, int N) {
    const int lane = threadIdx.x & 63, wid = threadIdx.x >> 6;
    int i = blockIdx.x * 256 + threadIdx.x;
    int v = (i < N) ? deg[i] : 0;
    int val = v;
#pragma unroll
    for (int off = 1; off < 64; off <<= 1) {
        int t = __shfl_up(val, off, 64);
        if (lane >= off) val += t;
    }
    __shared__ int ws[4];
    if (lane == 63) ws[wid] = val;
    __syncthreads();
    int pre = 0;
#pragma unroll
    for (int w = 0; w < 4; ++w) pre += (w < wid) ? ws[w] : 0;
    int incl = pre + val;
    if (i < N) rp[i] = incl - v;
    if (threadIdx.x == 255) bsum[blockIdx.x] = incl;
}

// ---------------- scan stage 2+3 + graph bounds, fused ----------------
__global__ __launch_bounds__(256) void scan23_kernel(int* __restrict__ rp,
                                                     const int* __restrict__ bsum,
                                                     const int* __restrict__ batch,
                                                     int* __restrict__ gstart,
                                                     int* __restrict__ gend,
                                                     int N, int E) {
    const int lane = threadIdx.x & 63, wid = threadIdx.x >> 6;
    const int b = blockIdx.x;
    int v = ((int)threadIdx.x < b) ? bsum[threadIdx.x] : 0;
#pragma unroll
    for (int m = 32; m >= 1; m >>= 1) v += __shfl_xor(v, m, 64);
    __shared__ int ws[4];
    if (lane == 0) ws[wid] = v;
    __syncthreads();
    int offset = ws[0] + ws[1] + ws[2] + ws[3];
    int i = b * 256 + threadIdx.x;
    if (i < N) {
        rp[i] += offset;
        int bb = batch[i];
        if (i == 0 || batch[i - 1] != bb) gstart[bb] = i;
        if (i == N - 1 || batch[i + 1] != bb) gend[bb] = i + 1;
    }
    if (b == 0 && threadIdx.x == 0) rp[N] = E;
}

// ---------------- FUSED: scatter (latency-bound) || linpq conv1 (compute-bound) ----------------
__global__ __launch_bounds__(256) void linpq_scat_kernel(
    const float* __restrict__ Av,
    const unsigned short* __restrict__ WpL, const float* __restrict__ bias,
    const unsigned short* __restrict__ WpP, const unsigned short* __restrict__ WpQ,
    const float* __restrict__ ab1,
    unsigned short* __restrict__ Dbf, unsigned char* __restrict__ Vf8,
    unsigned char* __restrict__ Pf8, unsigned char* __restrict__ Qf8, int M, int LB,
    const int* __restrict__ src, const int* __restrict__ dst,
    const float* __restrict__ aux, const int* __restrict__ rowptr,
    int* __restrict__ cursor, uint2* __restrict__ er, int E) {
    __shared__ char smem[32 * 136 * 2 + 32 * 128];   // 12800 B
    unsigned short (*lds)[136] = (unsigned short(*)[136])smem;
    unsigned char (*ldsV)[128] = (unsigned char(*)[128])(smem + 8704);
    unsigned char (*ldsP)[128] = (unsigned char(*)[128])smem;           // aliases lds
    unsigned char (*ldsQ)[128] = (unsigned char(*)[128])(smem + 4096);  // aliases lds

    const int b = blockIdx.x;
    int bi;
    bool isScat;
    if (b < 2 * LB) { isScat = ((b & 1) == 0); bi = b >> 1; }
    else            { isScat = true;           bi = LB + (b - 2 * LB); }

    if (isScat) {
        int e = bi * 256 + (int)threadIdx.x;
        if (e < E) {
            int d = dst[e];
            int pos = rowptr[d] + atomicAdd(&cursor[d], 1);
            float2 a = *(const float2*)(aux + 2 * e);
            uint2 r;
            r.x = (unsigned)src[e] | ((unsigned)d << 16);
            r.y = (unsigned)f2bf(a.x) | ((unsigned)f2bf(a.y) << 16);
            er[pos] = r;
        }
        return;
    }

    const int l = threadIdx.x & 63, w = threadIdx.x >> 6;
    const int tile = w >> 1, ch = w & 1;
    const int rowb = bi * 32;
    const int rowbase = rowb + tile * 16;
    const int r = rowbase + (l & 15);
    const int kc = (l >> 4) * 8;

    short8v afr[4];
    if (r < M) {
        const float* ap = Av + (size_t)r * 128 + kc;
#pragma unroll
        for (int ks = 0; ks < 4; ++ks) {
            float4 x0 = *(const float4*)(ap + ks * 32);
            float4 x1 = *(const float4*)(ap + ks * 32 + 4);
            unsigned short u[8] = {f2bf(x0.x), f2bf(x0.y), f2bf(x0.z), f2bf(x0.w),
                                   f2bf(x1.x), f2bf(x1.y), f2bf(x1.z), f2bf(x1.w)};
            afr[ks] = *(short8v*)u;
        }
    } else {
#pragma unroll
        for (int ks = 0; ks < 4; ++ks)
#pragma unroll
            for (int j = 0; j < 8; ++j) afr[ks][j] = 0;
    }

    f32x4 acc[4];
#pragma unroll
    for (int c = 0; c < 4; ++c)
#pragma unroll
        for (int j = 0; j < 4; ++j) acc[c][j] = 0.f;

    const short8v* wl = (const short8v*)WpL;
#pragma unroll
    for (int ks = 0; ks < 4; ++ks)
#pragma unroll
        for (int c = 0; c < 4; ++c)
            acc[c] = __builtin_amdgcn_mfma_f32_16x16x32_bf16(
                afr[ks], wl[(ks * 8 + ch * 4 + c) * 64 + l], acc[c], 0, 0, 0);

    const int lrb = tile * 16 + (l >> 4) * 4;
#pragma unroll
    for (int c = 0; c < 4; ++c) {
        int col = (ch * 4 + c) * 16 + (l & 15);
        float bv = bias[col];
#pragma unroll
        for (int j = 0; j < 4; ++j) {
            float v = acc[c][j] + bv;
            lds[lrb + j][col] = f2bf(v);
            ldsV[lrb + j][col] = f2fp8(v);
        }
    }
    __syncthreads();

    {
        int r2 = threadIdx.x >> 3, q2 = threadIdx.x & 7;  // 8 thr/row
        if (rowb + r2 < M) {
            *(uint4*)(Dbf + (size_t)(rowb + r2) * 128 + q2 * 16) =
                *(uint4*)&lds[r2][q2 * 16];
            *(uint4*)(Dbf + (size_t)(rowb + r2) * 128 + q2 * 16 + 8) =
                *(uint4*)&lds[r2][q2 * 16 + 8];
            *(uint4*)(Vf8 + (size_t)(rowb + r2) * 128 + q2 * 16) =
                *(uint4*)&ldsV[r2][q2 * 16];
        }
    }

    short8v xfr[4];
#pragma unroll
    for (int ks = 0; ks < 4; ++ks)
        xfr[ks] = *(const short8v*)&lds[tile * 16 + (l & 15)][kc + ks * 32];
    __syncthreads();   // close all reads of lds before aliased P/Q writes

    f32x4 accP[4], accQ[4];
#pragma unroll
    for (int c = 0; c < 4; ++c)
#pragma unroll
        for (int j = 0; j < 4; ++j) { accP[c][j] = 0.f; accQ[c][j] = 0.f; }

    const short8v* wp = (const short8v*)WpP;
    const short8v* wq = (const short8v*)WpQ;
#pragma unroll
    for (int ks = 0; ks < 4; ++ks)
#pragma unroll
        for (int c = 0; c < 4; ++c) {
            accP[c] = __builtin_amdgcn_mfma_f32_16x16x32_bf16(
                xfr[ks], wp[(ks * 8 + ch * 4 + c) * 64 + l], accP[c], 0, 0, 0);
            accQ[c] = __builtin_amdgcn_mfma_f32_16x16x32_bf16(
                xfr[ks], wq[(ks * 8 + ch * 4 + c) * 64 + l], accQ[c], 0, 0, 0);
        }

#pragma unroll
    for (int c = 0; c < 4; ++c) {
        int col = (ch * 4 + c) * 16 + (l & 15);
        float b1v = ab1[col];
#pragma unroll
        for (int j = 0; j < 4; ++j) {
            ldsP[lrb + j][col] = f2fp8(accP[c][j]);
            ldsQ[lrb + j][col] = f2fp8(accQ[c][j] + b1v);
        }
    }
    __syncthreads();
    {
        int r2 = threadIdx.x >> 3, q2 = threadIdx.x & 7;
        if (rowb + r2 < M) {
            *(uint4*)(Pf8 + (size_t)(rowb + r2) * 128 + q2 * 16) =
                *(uint4*)&ldsP[r2][q2 * 16];
            *(uint4*)(Qf8 + (size_t)(rowb + r2) * 128 + q2 * 16) =
                *(uint4*)&ldsQ[r2][q2 * 16];
        }
    }
}

// ---------------- two-phase MFMA GEMM (conv2, bf16 input), same LDS aliasing ----------------
__global__ __launch_bounds__(256) void linpq_kernel(const unsigned short* __restrict__ Av,
                                                    const unsigned short* __restrict__ WpL,
                                                    const float* __restrict__ bias,
                                                    const unsigned short* __restrict__ WpP,
                                                    const unsigned short* __restrict__ WpQ,
                                                    const float* __restrict__ ab1,
                                                    unsigned short* __restrict__ Dbf,
                                                    unsigned char* __restrict__ Vf8,
                                                    unsigned char* __restrict__ Pf8,
                                                    unsigned char* __restrict__ Qf8, int M) {
    __shared__ char smem[32 * 136 * 2 + 32 * 128];   // 12800 B
    unsigned short (*lds)[136] = (unsigned short(*)[136])smem;
    unsigned char (*ldsV)[128] = (unsigned char(*)[128])(smem + 8704);
    unsigned char (*ldsP)[128] = (unsigned char(*)[128])smem;
    unsigned char (*ldsQ)[128] = (unsigned char(*)[128])(smem + 4096);

    const int l = threadIdx.x & 63, w = threadIdx.x >> 6;
    const int tile = w >> 1, ch = w & 1;
    const int rowb = blockIdx.x * 32;
    const int rowbase = rowb + tile * 16;
    const int r = rowbase + (l & 15);
    const int kc = (l >> 4) * 8;

    short8v afr[4];
    if (r < M) {
        const unsigned short* ap = Av + (size_t)r * 128 + kc;
#pragma unroll
        for (int ks = 0; ks < 4; ++ks)
            afr[ks] = *(const short8v*)(ap + ks * 32);
    } else {
#pragma unroll
        for (int ks = 0; ks < 4; ++ks)
#pragma unroll
            for (int j = 0; j < 8; ++j) afr[ks][j] = 0;
    }

    f32x4 acc[4];
#pragma unroll
    for (int c = 0; c < 4; ++c)
#pragma unroll
        for (int j = 0; j < 4; ++j) acc[c][j] = 0.f;

    const short8v* wl = (const short8v*)WpL;
#pragma unroll
    for (int ks = 0; ks < 4; ++ks)
#pragma unroll
        for (int c = 0; c < 4; ++c)
            acc[c] = __builtin_amdgcn_mfma_f32_16x16x32_bf16(
                afr[ks], wl[(ks * 8 + ch * 4 + c) * 64 + l], acc[c], 0, 0, 0);

    const int lrb = tile * 16 + (l >> 4) * 4;
#pragma unroll
    for (int c = 0; c < 4; ++c) {
        int col = (ch * 4 + c) * 16 + (l & 15);
        float bv = bias[col];
#pragma unroll
        for (int j = 0; j < 4; ++j) {
            float v = acc[c][j] + bv;
            lds[lrb + j][col] = f2bf(v);
            ldsV[lrb + j][col] = f2fp8(v);
        }
    }
    __syncthreads();

    {
        int r2 = threadIdx.x >> 3, q2 = threadIdx.x & 7;
        if (rowb + r2 < M) {
            *(uint4*)(Dbf + (size_t)(rowb + r2) * 128 + q2 * 16) =
                *(uint4*)&lds[r2][q2 * 16];
            *(uint4*)(Dbf + (size_t)(rowb + r2) * 128 + q2 * 16 + 8) =
                *(uint4*)&lds[r2][q2 * 16 + 8];
            *(uint4*)(Vf8 + (size_t)(rowb + r2) * 128 + q2 * 16) =
                *(uint4*)&ldsV[r2][q2 * 16];
        }
    }

    short8v xfr[4];
#pragma unroll
    for (int ks = 0; ks < 4; ++ks)
        xfr[ks] = *(const short8v*)&lds[tile * 16 + (l & 15)][kc + ks * 32];
    __syncthreads();   // close all reads of lds before aliased P/Q writes

    f32x4 accP[4], accQ[4];
#pragma unroll
    for (int c = 0; c < 4; ++c)
#pragma unroll
        for (int j = 0; j < 4; ++j) { accP[c][j] = 0.f; accQ[c][j] = 0.f; }

    const short8v* wp = (const short8v*)WpP;
    const short8v* wq = (const short8v*)WpQ;
#pragma unroll
    for (int ks = 0; ks < 4; ++ks)
#pragma unroll
        for (int c = 0; c < 4; ++c) {
            accP[c] = __builtin_amdgcn_mfma_f32_16x16x32_bf16(
                xfr[ks], wp[(ks * 8 + ch * 4 + c) * 64 + l], accP[c], 0, 0, 0);
            accQ[c] = __builtin_amdgcn_mfma_f32_16x16x32_bf16(
                xfr[ks], wq[(ks * 8 + ch * 4 + c) * 64 + l], accQ[c], 0, 0, 0);
        }

#pragma unroll
    for (int c = 0; c < 4; ++c) {
        int col = (ch * 4 + c) * 16 + (l & 15);
        float b1v = ab1[col];
#pragma unroll
        for (int j = 0; j < 4; ++j) {
            ldsP[lrb + j][col] = f2fp8(accP[c][j]);
            ldsQ[lrb + j][col] = f2fp8(accQ[c][j] + b1v);
        }
    }
    __syncthreads();
    {
        int r2 = threadIdx.x >> 3, q2 = threadIdx.x & 7;
        if (rowb + r2 < M) {
            *(uint4*)(Pf8 + (size_t)(rowb + r2) * 128 + q2 * 16) =
                *(uint4*)&ldsP[r2][q2 * 16];
            *(uint4*)(Qf8 + (size_t)(rowb + r2) * 128 + q2 * 16) =
                *(uint4*)&ldsQ[r2][q2 * 16];
        }
    }
}

// ---------------- edge-parallel logits: 2 lanes/edge, 64 ch/lane, packed-f16 math ----------------
__global__ __launch_bounds__(256, 4) void attn_edge_kernel(
    const unsigned char* __restrict__ Pf8, const unsigned char* __restrict__ Qf8,
    const uint2* __restrict__ er,
    const float* __restrict__ wa0, const float* __restrict__ wa1,
    const float* __restrict__ lng, const float* __restrict__ lnb,
    const float* __restrict__ aw2, const float* __restrict__ ab2,
    float* __restrict__ wt, int E) {
    __shared__ float lwf[256];      // [arr:2][c:16][par:2][4] f32 (wa0, wa1)
    __shared__ unsigned lwh[192];   // [arr:3][c:16][par:2][pair:2] f16x2 (lng, lnb, aw2)
    {
        int idx = threadIdx.x;
        int arr = idx >> 7, rem = idx & 127;
        int par = rem >> 6, c = (rem >> 2) & 15, e = rem & 3;
        const float* sp = arr ? wa1 : wa0;
        lwf[(((arr * 16 + c) << 1) + par) * 4 + e] = sp[rem];
        if (idx < 192) {
            int a2 = idx >> 6, rem2 = idx & 63;
            int p2 = rem2 >> 5;
            int c2 = (rem2 >> 1) & 15;
            int pr = rem2 & 1;
            int chn = p2 * 64 + c2 * 4 + pr * 2;
            const float* s2 = (a2 == 0) ? lng : (a2 == 1) ? lnb : aw2;
            lwh[(((a2 * 16 + c2) << 1) + p2) * 2 + pr] = pkrtz(s2[chn], s2[chn + 1]);
        }
    }
    __syncthreads();
    const int slot = blockIdx.x * 128 + ((int)threadIdx.x >> 1);
    if (slot >= E) return;
    const int par = threadIdx.x & 1;
    const unsigned one2 = 0x3C003C00u;
    const unsigned zero2 = 0u;
    const int co = par << 6;

    uint2 ev = er[slot];
    const int sn = (int)(ev.x & 0xFFFFu);
    const int dn = (int)(ev.x >> 16);
    const float ax = bflo(ev.y), ay = bfhi(ev.y);

    const uint4* prow = (const uint4*)(Pf8 + (size_t)sn * 128 + co);
    const uint4* qrow = (const uint4*)(Qf8 + (size_t)dn * 128 + co);

    float r1 = 0.f, r2 = 0.f;
    unsigned tp[32];

#pragma unroll
    for (int g = 0; g < 4; ++g) {
        uint4 pv = prow[g];
        uint4 qv = qrow[g];
        unsigned pwa[4] = {pv.x, pv.y, pv.z, pv.w};
        unsigned qwa[4] = {qv.x, qv.y, qv.z, qv.w};
#pragma unroll
        for (int cc = 0; cc < 4; ++cc) {
            const int c = g * 4 + cc;
            f32x2 plo = __builtin_amdgcn_cvt_pk_f32_fp8((int)pwa[cc], false);
            f32x2 phi = __builtin_amdgcn_cvt_pk_f32_fp8((int)pwa[cc], true);
            f32x2 qlo = __builtin_amdgcn_cvt_pk_f32_fp8((int)qwa[cc], false);
            f32x2 qhi = __builtin_amdgcn_cvt_pk_f32_fp8((int)qwa[cc], true);
            float4 w0v = *(const float4*)&lwf[((c << 1) + par) * 4];
            float4 w1v = *(const float4*)&lwf[(((16 + c) << 1) + par) * 4];
            float t0 = plo[0] + qlo[0] + ax * w0v.x + ay * w1v.x;
            float t1 = plo[1] + qlo[1] + ax * w0v.y + ay * w1v.y;
            float t2 = phi[0] + qhi[0] + ax * w0v.z + ay * w1v.z;
            float t3 = phi[1] + qhi[1] + ax * w0v.w + ay * w1v.w;
            unsigned p0 = pkrtz(t0, t1);
            unsigned p1 = pkrtz(t2, t3);
            tp[2 * c] = p0;
            tp[2 * c + 1] = p1;
            r1 = fdot2a(p0, one2, r1);
            r1 = fdot2a(p1, one2, r1);
            r2 = fdot2a(p0, p0, r2);
            r2 = fdot2a(p1, p1, r2);
        }
    }
    r1 += __shfl_xor(r1, 1, 64);
    r2 += __shfl_xor(r2, 1, 64);
    float mean = r1 * (1.f / 128.f);
    float rstd = rsqrtf(r2 * (1.f / 128.f) - mean * mean + 1e-5f);
    float mr = mean * rstd;
    unsigned rstd2 = pkrtz(rstd, rstd);
    unsigned nmr2 = pkrtz(-mr, -mr);

    float dot = 0.f;
#pragma unroll
    for (int c = 0; c < 16; ++c) {
        unsigned base = (unsigned)(((c << 1) + par) * 2);
        uint2 gg = *(const uint2*)&lwh[base];
        uint2 ll = *(const uint2*)&lwh[64 + base];
        uint2 ww = *(const uint2*)&lwh[128 + base];
        unsigned u0 = pk_fma_f16(tp[2 * c], rstd2, nmr2);
        u0 = pk_fma_f16(u0, gg.x, ll.x);
        u0 = pk_max0_f16(u0, zero2);
        dot = fdot2a(u0, ww.x, dot);
        unsigned u1 = pk_fma_f16(tp[2 * c + 1], rstd2, nmr2);
        u1 = pk_fma_f16(u1, gg.y, ll.y);
        u1 = pk_max0_f16(u1, zero2);
        dot = fdot2a(u1, ww.y, dot);
    }
    dot += __shfl_xor(dot, 1, 64);
    if (par == 0) wt[slot] = __expf(dot + ab2[0]);
}

// ---------------- aggregation: 8 lanes/node, 16 ch/lane; 4-deep prefetch ----------------
template <int MODE>
__global__ __launch_bounds__(256) void aggr_kernel(
    const unsigned short* __restrict__ xlbf, const unsigned char* __restrict__ Vf8,
    const float* __restrict__ wt,
    const uint2* __restrict__ er, const int* __restrict__ rowptr,
    const float* __restrict__ g, const float* __restrict__ b,
    void* __restrict__ out, int N) {
    const int lane8 = threadIdx.x & 7;
    const int v = blockIdx.x * 32 + ((int)threadIdx.x >> 3);
    if (v >= N) return;
    const int jb = lane8 * 16;

    const int s0 = rowptr[v], s1e = rowptr[v + 1];
    const int deg = s1e - s0;
    float acc[16];
#pragma unroll
    for (int k = 0; k < 16; ++k) acc[k] = 0.f;
    float wsum = 0.f;

    uint4 pv[4];
    float pw[4];
#pragma unroll
    for (int k = 0; k < 4; ++k) { pv[k] = make_uint4(0, 0, 0, 0); pw[k] = 0.f; }
#define GATH2(idx, VV, WW)                                                       \
    if ((idx) < s1e) {                                                           \
        int sn_ = (int)(er[idx].x & 0xFFFFu);                                    \
        VV = *(const uint4*)(Vf8 + (size_t)sn_ * 128 + jb);                      \
        WW = wt[idx];                                                            \
    }
    GATH2(s0 + 0, pv[0], pw[0])
    GATH2(s0 + 1, pv[1], pw[1])
    GATH2(s0 + 2, pv[2], pw[2])
    GATH2(s0 + 3, pv[3], pw[3])

    for (int i = s0; i < s1e; i += 4) {
        uint4 c0 = pv[0], c1 = pv[1], c2 = pv[2], c3 = pv[3];
        float u0 = pw[0];
        float u1 = (i + 1 < s1e) ? pw[1] : 0.f;
        float u2 = (i + 2 < s1e) ? pw[2] : 0.f;
        float u3 = (i + 3 < s1e) ? pw[3] : 0.f;
        GATH2(i + 4, pv[0], pw[0])
        GATH2(i + 5, pv[1], pw[1])
        GATH2(i + 6, pv[2], pw[2])
        GATH2(i + 7, pv[3], pw[3])
        wsum += (u0 + u1) + (u2 + u3);
        unsigned d0[4] = {c0.x, c0.y, c0.z, c0.w};
        unsigned d1[4] = {c1.x, c1.y, c1.z, c1.w};
        unsigned d2[4] = {c2.x, c2.y, c2.z, c2.w};
        unsigned d3[4] = {c3.x, c3.y, c3.z, c3.w};
#pragma unroll
        for (int k = 0; k < 4; ++k) {
            f32x2 a0 = __builtin_amdgcn_cvt_pk_f32_fp8((int)d0[k], false);
            f32x2 a1 = __builtin_amdgcn_cvt_pk_f32_fp8((int)d0[k], true);
            f32x2 b0 = __builtin_amdgcn_cvt_pk_f32_fp8((int)d1[k], false);
            f32x2 b1 = __builtin_amdgcn_cvt_pk_f32_fp8((int)d1[k], true);
            f32x2 e0 = __builtin_amdgcn_cvt_pk_f32_fp8((int)d2[k], false);
            f32x2 e1 = __builtin_amdgcn_cvt_pk_f32_fp8((int)d2[k], true);
            f32x2 f0 = __builtin_amdgcn_cvt_pk_f32_fp8((int)d3[k], false);
            f32x2 f1 = __builtin_amdgcn_cvt_pk_f32_fp8((int)d3[k], true);
            acc[4 * k + 0] += (u0 * a0[0] + u1 * b0[0]) + (u2 * e0[0] + u3 * f0[0]);
            acc[4 * k + 1] += (u0 * a0[1] + u1 * b0[1]) + (u2 * e0[1] + u3 * f0[1]);
            acc[4 * k + 2] += (u0 * a1[0] + u1 * b1[0]) + (u2 * e1[0] + u3 * f1[0]);
            acc[4 * k + 3] += (u0 * a1[1] + u1 * b1[1]) + (u2 * e1[1] + u3 * f1[1]);
        }
    }
#undef GATH2

    const float ns = (deg > 0) ? 1.f / (wsum * (float)deg) : 0.f;
    float o[16];
    const unsigned short* xp = xlbf + (size_t)v * 128 + jb;
    uint4 xa = *(const uint4*)xp;
    uint4 xb = *(const uint4*)(xp + 8);
    unsigned xw[8] = {xa.x, xa.y, xa.z, xa.w, xb.x, xb.y, xb.z, xb.w};
#pragma unroll
    for (int k = 0; k < 8; ++k) {
        o[2 * k] = bflo(xw[k]) + acc[2 * k] * ns;
        o[2 * k + 1] = bfhi(xw[k]) + acc[2 * k + 1] * ns;
    }

    if (MODE == 0) {
        unsigned short* op = (unsigned short*)out + (size_t)v * 128 + jb;
        unsigned opk[8];
#pragma unroll
        for (int k = 0; k < 8; ++k)
            opk[k] = (unsigned)f2bf(fmaxf(o[2 * k], 0.f)) |
                     ((unsigned)f2bf(fmaxf(o[2 * k + 1], 0.f)) << 16);
        *(uint4*)op = make_uint4(opk[0], opk[1], opk[2], opk[3]);
        *(uint4*)(op + 8) = make_uint4(opk[4], opk[5], opk[6], opk[7]);
    } else {
        float r1 = 0.f, r2 = 0.f;
#pragma unroll
        for (int k = 0; k < 16; ++k) { r1 += o[k]; r2 = fmaf(o[k], o[k], r2); }
#pragma unroll
        for (int mk = 4; mk >= 1; mk >>= 1) {
            r1 += __shfl_xor(r1, mk, 64);
            r2 += __shfl_xor(r2, mk, 64);
        }
        float mean = r1 * (1.f / 128.f);
        float rstd = rsqrtf(r2 * (1.f / 128.f) - mean * mean + 1e-5f);
        float mr = mean * rstd;
        float* op = (float*)out + (size_t)v * 128 + jb;
#pragma unroll
        for (int k4 = 0; k4 < 4; ++k4) {
            float4 gv = *(const float4*)(g + jb + 4 * k4);
            float4 bv = *(const float4*)(b + jb + 4 * k4);
            float4 r;
            r.x = fmaf(fmaf(o[4 * k4 + 0], rstd, -mr), gv.x, bv.x);
            r.y = fmaf(fmaf(o[4 * k4 + 1], rstd, -mr), gv.y, bv.y);
            r.z = fmaf(fmaf(o[4 * k4 + 2], rstd, -mr), gv.z, bv.z);
            r.w = fmaf(fmaf(o[4 * k4 + 3], rstd, -mr), gv.w, bv.w);
            *(float4*)(op + 4 * k4) = r;
        }
    }
}

// ---------------- pool stage 1: per-(graph, slice) partial max ----------------
__global__ __launch_bounds__(128) void pool1_kernel(const float* __restrict__ h,
                                                    const int* __restrict__ gstart,
                                                    const int* __restrict__ gend,
                                                    float* __restrict__ part) {
    int gph = blockIdx.x >> 4;
    int sl = blockIdx.x & 15;
    int col = threadIdx.x;
    int s = gstart[gph], e = gend[gph];
    float m = -INFINITY;
    for (int r = s + sl; r < e; r += 16) m = fmaxf(m, h[(size_t)r * 128 + col]);
    part[(size_t)blockIdx.x * 128 + col] = m;
}

// ---------------- classifier head (folds pool stage 2) ----------------
__global__ __launch_bounds__(128) void cls_kernel(const float* __restrict__ part,
                                                  const float* __restrict__ cw,
                                                  const float* __restrict__ cb,
                                                  float* __restrict__ out) {
    int gph = blockIdx.x, c = threadIdx.x;
    float m = -INFINITY;
#pragma unroll
    for (int sl = 0; sl < 16; ++sl) m = fmaxf(m, part[(size_t)(gph * 16 + sl) * 128 + c]);
    __shared__ float f[128];
    f[c] = m;
    __syncthreads();
    float acc = cb[c];
#pragma unroll 8
    for (int k = 0; k < 128; ++k) acc += f[k] * cw[k * 128 + c];
    out[gph * 128 + c] = acc;
}

// ---------------- launch ----------------
extern "C" void kernel_launch(void* const* d_in, const int* in_sizes, int n_in,
                              void* d_out, int out_size, void* d_ws, size_t ws_size,
                              hipStream_t stream) {
    const float* x      = (const float*)d_in[0];
    const int*   ei     = (const int*)d_in[1];
    const float* aux    = (const float*)d_in[2];
    const int*   batch  = (const int*)d_in[3];
    const float* w_lin1 = (const float*)d_in[4];
    const float* b_lin1 = (const float*)d_in[5];
    const float* aw1_1  = (const float*)d_in[6];
    const float* ab1_1  = (const float*)d_in[7];
    const float* lng1   = (const float*)d_in[8];
    const float* lnb1   = (const float*)d_in[9];
    const float* aw2_1  = (const float*)d_in[10];
    const float* ab2_1  = (const float*)d_in[11];
    const float* w_lin2 = (const float*)d_in[12];
    const float* b_lin2 = (const float*)d_in[13];
    const float* aw1_2  = (const float*)d_in[14];
    const float* ab1_2  = (const float*)d_in[15];
    const float* lng2   = (const float*)d_in[16];
    const float* lnb2   = (const float*)d_in[17];
    const float* aw2_2  = (const float*)d_in[18];
    const float* ab2_2  = (const float*)d_in[19];
    const float* cls_w  = (const float*)d_in[20];
    const float* cls_b  = (const float*)d_in[21];
    const float* norm_g = (const float*)d_in[22];
    const float* norm_b = (const float*)d_in[23];

    const int N = in_sizes[0] / 128;
    const int E = in_sizes[2] / 2;
    const int G = 64;
    const int* src = ei;
    const int* dst = ei + E;

    // workspace layout: 16B-aligned buffers first
    char* wsp = (char*)d_ws;
    unsigned short* xlbf  = (unsigned short*)wsp;   wsp += (size_t)N * 128 * 2;
    unsigned short* h1bf  = (unsigned short*)wsp;   wsp += (size_t)N * 128 * 2;
    unsigned char*  Pf8   = (unsigned char*)wsp;    wsp += (size_t)N * 128;
    unsigned char*  Qf8   = (unsigned char*)wsp;    wsp += (size_t)N * 128;
    unsigned char*  Vf8   = (unsigned char*)wsp;    wsp += (size_t)N * 128;
    unsigned short* wpack = (unsigned short*)wsp;   wsp += 6 * 16384 * 2;
    float*          part  = (float*)wsp;            wsp += (size_t)1024 * 128 * 4;
    uint2*          er    = (uint2*)wsp;            wsp += (size_t)E * 8;
    float*          wt    = (float*)wsp;            wsp += (size_t)E * 4;
    int*            bsum    = (int*)wsp;            wsp += 256 * 4;
    int*            deg     = (int*)wsp;            wsp += (size_t)N * 4;
    int*            cursor  = (int*)wsp;            wsp += (size_t)N * 4;
    int*            rowptr  = (int*)wsp;            wsp += (size_t)(N + 1) * 4;
    int*            gstart  = (int*)wsp;            wsp += (size_t)G * 4;
    int*            gend    = (int*)wsp;            wsp += (size_t)G * 4;

    unsigned short* wp_lin1 = wpack;
    unsigned short* wp_s1   = wpack + 16384;
    unsigned short* wp_d1   = wpack + 2 * 16384;
    unsigned short* wp_lin2 = wpack + 3 * 16384;
    unsigned short* wp_s2   = wpack + 4 * 16384;
    unsigned short* wp_d2   = wpack + 5 * 16384;

    float* hout   = (float*)d_out;
    float* clsout = hout + (size_t)N * 128;

    hipMemsetAsync(deg, 0, (size_t)(2 * N) * sizeof(int), stream);      // deg + cursor
    hipMemsetAsync(gstart, 0, (size_t)(2 * G) * sizeof(int), stream);

    const int eb = (E + 255) / 256;
    const int nb = (N + 255) / 256;
    const int lb = (N + 31) / 32;
    const int atb = (E + 127) / 128;
    const int agb = (N + 31) / 32;

    prep_kernel<<<384 + eb, 256, 0, stream>>>(w_lin1, aw1_1, aw1_1 + 128 * 128,
                                              w_lin2, aw1_2, aw1_2 + 128 * 128,
                                              wpack, dst, deg, E);
    scan1_kernel<<<nb, 256, 0, stream>>>(deg, rowptr, bsum, N);
    scan23_kernel<<<nb, 256, 0, stream>>>(rowptr, bsum, batch, gstart, gend, N, E);

    // ---- conv1 (scatter overlapped with linpq) ----
    linpq_scat_kernel<<<lb + eb, 256, 0, stream>>>(x, wp_lin1, b_lin1, wp_s1, wp_d1,
                                                   ab1_1, xlbf, Vf8, Pf8, Qf8, N, lb,
                                                   src, dst, aux, rowptr, cursor, er, E);
    attn_edge_kernel<<<atb, 256, 0, stream>>>(Pf8, Qf8, er,
                                              aw1_1 + 256 * 128, aw1_1 + 257 * 128,
                                              lng1, lnb1, aw2_1, ab2_1, wt, E);
    aggr_kernel<0><<<agb, 256, 0, stream>>>(xlbf, Vf8, wt, er, rowptr,
                                            nullptr, nullptr, h1bf, N);
    // ---- conv2 ----
    linpq_kernel<<<lb, 256, 0, stream>>>(h1bf, wp_lin2, b_lin2, wp_s2, wp_d2, ab1_2,
                                         xlbf, Vf8, Pf8, Qf8, N);
    attn_edge_kernel<<<atb, 256, 0, stream>>>(Pf8, Qf8, er,
                                              aw1_2 + 256 * 128, aw1_2 + 257 * 128,
                                              lng2, lnb2, aw2_2, ab2_2, wt, E);
    aggr_kernel<1><<<agb, 256, 0, stream>>>(xlbf, Vf8, wt, er, rowptr,
                                            norm_g, norm_b, hout, N);
    // ---- head ----
    pool1_kernel<<<G * 16, 128, 0, stream>>>(hout, gstart, gend, part);
    cls_kernel<<<G, 128, 0, stream>>>(part, cls_w, cls_b, clsout);
}

// Round 26
// 216.867 us; speedup vs baseline: 1.0605x; 1.0595x over previous
//
#include <hip/hip_runtime.h>
#include <math.h>

typedef __attribute__((ext_vector_type(8))) short short8v;   // 8 bf16 (4 VGPR)
typedef __attribute__((ext_vector_type(4))) float f32x4;
typedef __attribute__((ext_vector_type(2))) float f32x2;

// ---------------- helpers ----------------
__device__ __forceinline__ unsigned short f2bf(float f) {
    union { float f; unsigned int u; } v; v.f = f;
    unsigned int r = v.u + 0x7FFFu + ((v.u >> 16) & 1u);
    return (unsigned short)(r >> 16);
}
__device__ __forceinline__ float bflo(unsigned int v) {
    union { unsigned int u; float f; } x; x.u = v << 16; return x.f;
}
__device__ __forceinline__ float bfhi(unsigned int v) {
    union { unsigned int u; float f; } x; x.u = v & 0xFFFF0000u; return x.f;
}
__device__ __forceinline__ unsigned char f2fp8(float f) {
    return (unsigned char)(__builtin_amdgcn_cvt_pk_fp8_f32(f, f, 0, false) & 0xFF);
}
__device__ __forceinline__ unsigned pkrtz(float a, float b) {
    unsigned d;
    asm("v_cvt_pkrtz_f16_f32 %0, %1, %2" : "=v"(d) : "v"(a), "v"(b));
    return d;
}
__device__ __forceinline__ float fdot2a(unsigned a, unsigned b, float c) {
    float d;
    asm("v_dot2_f32_f16 %0, %1, %2, %3" : "=v"(d) : "v"(a), "v"(b), "v"(c));
    return d;
}
__device__ __forceinline__ unsigned pk_fma_f16(unsigned a, unsigned b, unsigned c) {
    unsigned d;
    asm("v_pk_fma_f16 %0, %1, %2, %3" : "=v"(d) : "v"(a), "v"(b), "v"(c));
    return d;
}
__device__ __forceinline__ unsigned pk_max0_f16(unsigned a, unsigned z) {
    unsigned d;
    asm("v_pk_max_f16 %0, %1, %2" : "=v"(d) : "v"(a), "v"(z));
    return d;
}

// ---------------- prep: weight pack (384 blocks) + dst histogram (rest) ----------------
__global__ __launch_bounds__(256) void prep_kernel(const float* __restrict__ s0,
                                                   const float* __restrict__ s1,
                                                   const float* __restrict__ s2,
                                                   const float* __restrict__ s3,
                                                   const float* __restrict__ s4,
                                                   const float* __restrict__ s5,
                                                   unsigned short* __restrict__ Wp,
                                                   const int* __restrict__ dst,
                                                   int* __restrict__ deg, int E) {
    int b = blockIdx.x;
    if (b < 384) {
        int which = b >> 6;
        const float* W = (which == 0) ? s0 : (which == 1) ? s1 : (which == 2) ? s2
                       : (which == 3) ? s3 : (which == 4) ? s4 : s5;
        int t = (b & 63) * 256 + threadIdx.x;
        int j = t & 7, l = (t >> 3) & 63, ct = (t >> 9) & 7, ks = t >> 12;
        int k = ks * 32 + (l >> 4) * 8 + j;
        int n = ct * 16 + (l & 15);
        Wp[which * 16384 + t] = f2bf(W[k * 128 + n]);
    } else {
        int e = (b - 384) * 256 + threadIdx.x;
        if (e < E) atomicAdd(&deg[dst[e]], 1);
    }
}

// ---------------- scan stage 1 ----------------
__global__ __launch_bounds__(256) void scan1_kernel(const int* __restrict__ deg,
                                                    int* __restrict__ rp,
                                                    int* __restrict__ bsum, int N) {
    const int lane = threadIdx.x & 63, wid = threadIdx.x >> 6;
    int i = blockIdx.x * 256 + threadIdx.x;
    int v = (i < N) ? deg[i] : 0;
    int val = v;
#pragma unroll
    for (int off = 1; off < 64; off <<= 1) {
        int t = __shfl_up(val, off, 64);
        if (lane >= off) val += t;
    }
    __shared__ int ws[4];
    if (lane == 63) ws[wid] = val;
    __syncthreads();
    int pre = 0;
#pragma unroll
    for (int w = 0; w < 4; ++w) pre += (w < wid) ? ws[w] : 0;
    int incl = pre + val;
    if (i < N) rp[i] = incl - v;
    if (threadIdx.x == 255) bsum[blockIdx.x] = incl;
}

// ---------------- scan stage 2+3 + graph bounds, fused ----------------
__global__ __launch_bounds__(256) void scan23_kernel(int* __restrict__ rp,
                                                     const int* __restrict__ bsum,
                                                     const int* __restrict__ batch,
                                                     int* __restrict__ gstart,
                                                     int* __restrict__ gend,
                                                     int N, int E) {
    const int lane = threadIdx.x & 63, wid = threadIdx.x >> 6;
    const int b = blockIdx.x;
    int v = ((int)threadIdx.x < b) ? bsum[threadIdx.x] : 0;
#pragma unroll
    for (int m = 32; m >= 1; m >>= 1) v += __shfl_xor(v, m, 64);
    __shared__ int ws[4];
    if (lane == 0) ws[wid] = v;
    __syncthreads();
    int offset = ws[0] + ws[1] + ws[2] + ws[3];
    int i = b * 256 + threadIdx.x;
    if (i < N) {
        rp[i] += offset;
        int bb = batch[i];
        if (i == 0 || batch[i - 1] != bb) gstart[bb] = i;
        if (i == N - 1 || batch[i + 1] != bb) gend[bb] = i + 1;
    }
    if (b == 0 && threadIdx.x == 0) rp[N] = E;
}

// ---------------- FUSED: scatter (latency-bound) || linpq conv1 (compute-bound) ----------------
__global__ __launch_bounds__(256) void linpq_scat_kernel(
    const float* __restrict__ Av,
    const unsigned short* __restrict__ WpL, const float* __restrict__ bias,
    const unsigned short* __restrict__ WpP, const unsigned short* __restrict__ WpQ,
    const float* __restrict__ ab1,
    unsigned short* __restrict__ Dbf, unsigned char* __restrict__ Vf8,
    unsigned char* __restrict__ Pf8, unsigned char* __restrict__ Qf8, int M, int LB,
    const int* __restrict__ src, const int* __restrict__ dst,
    const float* __restrict__ aux, const int* __restrict__ rowptr,
    int* __restrict__ cursor, uint2* __restrict__ er, int E) {
    __shared__ char smem[32 * 136 * 2 + 32 * 128];   // 12800 B
    unsigned short (*lds)[136] = (unsigned short(*)[136])smem;
    unsigned char (*ldsV)[128] = (unsigned char(*)[128])(smem + 8704);
    unsigned char (*ldsP)[128] = (unsigned char(*)[128])smem;           // aliases lds
    unsigned char (*ldsQ)[128] = (unsigned char(*)[128])(smem + 4096);  // aliases lds

    const int b = blockIdx.x;
    int bi;
    bool isScat;
    if (b < 2 * LB) { isScat = ((b & 1) == 0); bi = b >> 1; }
    else            { isScat = true;           bi = LB + (b - 2 * LB); }

    if (isScat) {
        int e = bi * 256 + (int)threadIdx.x;
        if (e < E) {
            int d = dst[e];
            int pos = rowptr[d] + atomicAdd(&cursor[d], 1);
            float2 a = *(const float2*)(aux + 2 * e);
            uint2 r;
            r.x = (unsigned)src[e] | ((unsigned)d << 16);
            r.y = (unsigned)f2bf(a.x) | ((unsigned)f2bf(a.y) << 16);
            er[pos] = r;
        }
        return;
    }

    const int l = threadIdx.x & 63, w = threadIdx.x >> 6;
    const int tile = w >> 1, ch = w & 1;
    const int rowb = bi * 32;
    const int rowbase = rowb + tile * 16;
    const int r = rowbase + (l & 15);
    const int kc = (l >> 4) * 8;

    short8v afr[4];
    if (r < M) {
        const float* ap = Av + (size_t)r * 128 + kc;
#pragma unroll
        for (int ks = 0; ks < 4; ++ks) {
            float4 x0 = *(const float4*)(ap + ks * 32);
            float4 x1 = *(const float4*)(ap + ks * 32 + 4);
            unsigned short u[8] = {f2bf(x0.x), f2bf(x0.y), f2bf(x0.z), f2bf(x0.w),
                                   f2bf(x1.x), f2bf(x1.y), f2bf(x1.z), f2bf(x1.w)};
            afr[ks] = *(short8v*)u;
        }
    } else {
#pragma unroll
        for (int ks = 0; ks < 4; ++ks)
#pragma unroll
            for (int j = 0; j < 8; ++j) afr[ks][j] = 0;
    }

    f32x4 acc[4];
#pragma unroll
    for (int c = 0; c < 4; ++c)
#pragma unroll
        for (int j = 0; j < 4; ++j) acc[c][j] = 0.f;

    const short8v* wl = (const short8v*)WpL;
#pragma unroll
    for (int ks = 0; ks < 4; ++ks)
#pragma unroll
        for (int c = 0; c < 4; ++c)
            acc[c] = __builtin_amdgcn_mfma_f32_16x16x32_bf16(
                afr[ks], wl[(ks * 8 + ch * 4 + c) * 64 + l], acc[c], 0, 0, 0);

    const int lrb = tile * 16 + (l >> 4) * 4;
#pragma unroll
    for (int c = 0; c < 4; ++c) {
        int col = (ch * 4 + c) * 16 + (l & 15);
        float bv = bias[col];
#pragma unroll
        for (int j = 0; j < 4; ++j) {
            float v = acc[c][j] + bv;
            lds[lrb + j][col] = f2bf(v);
            ldsV[lrb + j][col] = f2fp8(v);
        }
    }
    __syncthreads();

    {
        int r2 = threadIdx.x >> 3, q2 = threadIdx.x & 7;  // 8 thr/row
        if (rowb + r2 < M) {
            *(uint4*)(Dbf + (size_t)(rowb + r2) * 128 + q2 * 16) =
                *(uint4*)&lds[r2][q2 * 16];
            *(uint4*)(Dbf + (size_t)(rowb + r2) * 128 + q2 * 16 + 8) =
                *(uint4*)&lds[r2][q2 * 16 + 8];
            *(uint4*)(Vf8 + (size_t)(rowb + r2) * 128 + q2 * 16) =
                *(uint4*)&ldsV[r2][q2 * 16];
        }
    }

    short8v xfr[4];
#pragma unroll
    for (int ks = 0; ks < 4; ++ks)
        xfr[ks] = *(const short8v*)&lds[tile * 16 + (l & 15)][kc + ks * 32];
    __syncthreads();   // close all reads of lds before aliased P/Q writes

    f32x4 accP[4], accQ[4];
#pragma unroll
    for (int c = 0; c < 4; ++c)
#pragma unroll
        for (int j = 0; j < 4; ++j) { accP[c][j] = 0.f; accQ[c][j] = 0.f; }

    const short8v* wp = (const short8v*)WpP;
    const short8v* wq = (const short8v*)WpQ;
#pragma unroll
    for (int ks = 0; ks < 4; ++ks)
#pragma unroll
        for (int c = 0; c < 4; ++c) {
            accP[c] = __builtin_amdgcn_mfma_f32_16x16x32_bf16(
                xfr[ks], wp[(ks * 8 + ch * 4 + c) * 64 + l], accP[c], 0, 0, 0);
            accQ[c] = __builtin_amdgcn_mfma_f32_16x16x32_bf16(
                xfr[ks], wq[(ks * 8 + ch * 4 + c) * 64 + l], accQ[c], 0, 0, 0);
        }

#pragma unroll
    for (int c = 0; c < 4; ++c) {
        int col = (ch * 4 + c) * 16 + (l & 15);
        float b1v = ab1[col];
#pragma unroll
        for (int j = 0; j < 4; ++j) {
            ldsP[lrb + j][col] = f2fp8(accP[c][j]);
            ldsQ[lrb + j][col] = f2fp8(accQ[c][j] + b1v);
        }
    }
    __syncthreads();
    {
        int r2 = threadIdx.x >> 3, q2 = threadIdx.x & 7;
        if (rowb + r2 < M) {
            *(uint4*)(Pf8 + (size_t)(rowb + r2) * 128 + q2 * 16) =
                *(uint4*)&ldsP[r2][q2 * 16];
            *(uint4*)(Qf8 + (size_t)(rowb + r2) * 128 + q2 * 16) =
                *(uint4*)&ldsQ[r2][q2 * 16];
        }
    }
}

// ---------------- two-phase MFMA GEMM (conv2, bf16 input), same LDS aliasing ----------------
__global__ __launch_bounds__(256) void linpq_kernel(const unsigned short* __restrict__ Av,
                                                    const unsigned short* __restrict__ WpL,
                                                    const float* __restrict__ bias,
                                                    const unsigned short* __restrict__ WpP,
                                                    const unsigned short* __restrict__ WpQ,
                                                    const float* __restrict__ ab1,
                                                    unsigned short* __restrict__ Dbf,
                                                    unsigned char* __restrict__ Vf8,
                                                    unsigned char* __restrict__ Pf8,
                                                    unsigned char* __restrict__ Qf8, int M) {
    __shared__ char smem[32 * 136 * 2 + 32 * 128];   // 12800 B
    unsigned short (*lds)[136] = (unsigned short(*)[136])smem;
    unsigned char (*ldsV)[128] = (unsigned char(*)[128])(smem + 8704);
    unsigned char (*ldsP)[128] = (unsigned char(*)[128])smem;
    unsigned char (*ldsQ)[128] = (unsigned char(*)[128])(smem + 4096);

    const int l = threadIdx.x & 63, w = threadIdx.x >> 6;
    const int tile = w >> 1, ch = w & 1;
    const int rowb = blockIdx.x * 32;
    const int rowbase = rowb + tile * 16;
    const int r = rowbase + (l & 15);
    const int kc = (l >> 4) * 8;

    short8v afr[4];
    if (r < M) {
        const unsigned short* ap = Av + (size_t)r * 128 + kc;
#pragma unroll
        for (int ks = 0; ks < 4; ++ks)
            afr[ks] = *(const short8v*)(ap + ks * 32);
    } else {
#pragma unroll
        for (int ks = 0; ks < 4; ++ks)
#pragma unroll
            for (int j = 0; j < 8; ++j) afr[ks][j] = 0;
    }

    f32x4 acc[4];
#pragma unroll
    for (int c = 0; c < 4; ++c)
#pragma unroll
        for (int j = 0; j < 4; ++j) acc[c][j] = 0.f;

    const short8v* wl = (const short8v*)WpL;
#pragma unroll
    for (int ks = 0; ks < 4; ++ks)
#pragma unroll
        for (int c = 0; c < 4; ++c)
            acc[c] = __builtin_amdgcn_mfma_f32_16x16x32_bf16(
                afr[ks], wl[(ks * 8 + ch * 4 + c) * 64 + l], acc[c], 0, 0, 0);

    const int lrb = tile * 16 + (l >> 4) * 4;
#pragma unroll
    for (int c = 0; c < 4; ++c) {
        int col = (ch * 4 + c) * 16 + (l & 15);
        float bv = bias[col];
#pragma unroll
        for (int j = 0; j < 4; ++j) {
            float v = acc[c][j] + bv;
            lds[lrb + j][col] = f2bf(v);
            ldsV[lrb + j][col] = f2fp8(v);
        }
    }
    __syncthreads();

    {
        int r2 = threadIdx.x >> 3, q2 = threadIdx.x & 7;
        if (rowb + r2 < M) {
            *(uint4*)(Dbf + (size_t)(rowb + r2) * 128 + q2 * 16) =
                *(uint4*)&lds[r2][q2 * 16];
            *(uint4*)(Dbf + (size_t)(rowb + r2) * 128 + q2 * 16 + 8) =
                *(uint4*)&lds[r2][q2 * 16 + 8];
            *(uint4*)(Vf8 + (size_t)(rowb + r2) * 128 + q2 * 16) =
                *(uint4*)&ldsV[r2][q2 * 16];
        }
    }

    short8v xfr[4];
#pragma unroll
    for (int ks = 0; ks < 4; ++ks)
        xfr[ks] = *(const short8v*)&lds[tile * 16 + (l & 15)][kc + ks * 32];
    __syncthreads();   // close all reads of lds before aliased P/Q writes

    f32x4 accP[4], accQ[4];
#pragma unroll
    for (int c = 0; c < 4; ++c)
#pragma unroll
        for (int j = 0; j < 4; ++j) { accP[c][j] = 0.f; accQ[c][j] = 0.f; }

    const short8v* wp = (const short8v*)WpP;
    const short8v* wq = (const short8v*)WpQ;
#pragma unroll
    for (int ks = 0; ks < 4; ++ks)
#pragma unroll
        for (int c = 0; c < 4; ++c) {
            accP[c] = __builtin_amdgcn_mfma_f32_16x16x32_bf16(
                xfr[ks], wp[(ks * 8 + ch * 4 + c) * 64 + l], accP[c], 0, 0, 0);
            accQ[c] = __builtin_amdgcn_mfma_f32_16x16x32_bf16(
                xfr[ks], wq[(ks * 8 + ch * 4 + c) * 64 + l], accQ[c], 0, 0, 0);
        }

#pragma unroll
    for (int c = 0; c < 4; ++c) {
        int col = (ch * 4 + c) * 16 + (l & 15);
        float b1v = ab1[col];
#pragma unroll
        for (int j = 0; j < 4; ++j) {
            ldsP[lrb + j][col] = f2fp8(accP[c][j]);
            ldsQ[lrb + j][col] = f2fp8(accQ[c][j] + b1v);
        }
    }
    __syncthreads();
    {
        int r2 = threadIdx.x >> 3, q2 = threadIdx.x & 7;
        if (rowb + r2 < M) {
            *(uint4*)(Pf8 + (size_t)(rowb + r2) * 128 + q2 * 16) =
                *(uint4*)&ldsP[r2][q2 * 16];
            *(uint4*)(Qf8 + (size_t)(rowb + r2) * 128 + q2 * 16) =
                *(uint4*)&ldsQ[r2][q2 * 16];
        }
    }
}

// ---------------- edge-parallel logits: 2 lanes/edge, 64 ch/lane, packed-f16 math ----------------
__global__ __launch_bounds__(256, 4) void attn_edge_kernel(
    const unsigned char* __restrict__ Pf8, const unsigned char* __restrict__ Qf8,
    const uint2* __restrict__ er,
    const float* __restrict__ wa0, const float* __restrict__ wa1,
    const float* __restrict__ lng, const float* __restrict__ lnb,
    const float* __restrict__ aw2, const float* __restrict__ ab2,
    float* __restrict__ wt, int E) {
    __shared__ float lwf[256];      // [arr:2][c:16][par:2][4] f32 (wa0, wa1)
    __shared__ unsigned lwh[192];   // [arr:3][c:16][par:2][pair:2] f16x2 (lng, lnb, aw2)
    {
        int idx = threadIdx.x;
        int arr = idx >> 7, rem = idx & 127;
        int par = rem >> 6, c = (rem >> 2) & 15, e = rem & 3;
        const float* sp = arr ? wa1 : wa0;
        lwf[(((arr * 16 + c) << 1) + par) * 4 + e] = sp[rem];
        if (idx < 192) {
            int a2 = idx >> 6, rem2 = idx & 63;
            int p2 = rem2 >> 5;
            int c2 = (rem2 >> 1) & 15;
            int pr = rem2 & 1;
            int chn = p2 * 64 + c2 * 4 + pr * 2;
            const float* s2 = (a2 == 0) ? lng : (a2 == 1) ? lnb : aw2;
            lwh[(((a2 * 16 + c2) << 1) + p2) * 2 + pr] = pkrtz(s2[chn], s2[chn + 1]);
        }
    }
    __syncthreads();
    const int slot = blockIdx.x * 128 + ((int)threadIdx.x >> 1);
    if (slot >= E) return;
    const int par = threadIdx.x & 1;
    const unsigned one2 = 0x3C003C00u;
    const unsigned zero2 = 0u;
    const int co = par << 6;

    uint2 ev = er[slot];
    const int sn = (int)(ev.x & 0xFFFFu);
    const int dn = (int)(ev.x >> 16);
    const float ax = bflo(ev.y), ay = bfhi(ev.y);

    const uint4* prow = (const uint4*)(Pf8 + (size_t)sn * 128 + co);
    const uint4* qrow = (const uint4*)(Qf8 + (size_t)dn * 128 + co);

    float r1 = 0.f, r2 = 0.f;
    unsigned tp[32];

#pragma unroll
    for (int g = 0; g < 4; ++g) {
        uint4 pv = prow[g];
        uint4 qv = qrow[g];
        unsigned pwa[4] = {pv.x, pv.y, pv.z, pv.w};
        unsigned qwa[4] = {qv.x, qv.y, qv.z, qv.w};
#pragma unroll
        for (int cc = 0; cc < 4; ++cc) {
            const int c = g * 4 + cc;
            f32x2 plo = __builtin_amdgcn_cvt_pk_f32_fp8((int)pwa[cc], false);
            f32x2 phi = __builtin_amdgcn_cvt_pk_f32_fp8((int)pwa[cc], true);
            f32x2 qlo = __builtin_amdgcn_cvt_pk_f32_fp8((int)qwa[cc], false);
            f32x2 qhi = __builtin_amdgcn_cvt_pk_f32_fp8((int)qwa[cc], true);
            float4 w0v = *(const float4*)&lwf[((c << 1) + par) * 4];
            float4 w1v = *(const float4*)&lwf[(((16 + c) << 1) + par) * 4];
            float t0 = plo[0] + qlo[0] + ax * w0v.x + ay * w1v.x;
            float t1 = plo[1] + qlo[1] + ax * w0v.y + ay * w1v.y;
            float t2 = phi[0] + qhi[0] + ax * w0v.z + ay * w1v.z;
            float t3 = phi[1] + qhi[1] + ax * w0v.w + ay * w1v.w;
            unsigned p0 = pkrtz(t0, t1);
            unsigned p1 = pkrtz(t2, t3);
            tp[2 * c] = p0;
            tp[2 * c + 1] = p1;
            r1 = fdot2a(p0, one2, r1);
            r1 = fdot2a(p1, one2, r1);
            r2 = fdot2a(p0, p0, r2);
            r2 = fdot2a(p1, p1, r2);
        }
    }
    r1 += __shfl_xor(r1, 1, 64);
    r2 += __shfl_xor(r2, 1, 64);
    float mean = r1 * (1.f / 128.f);
    float rstd = rsqrtf(r2 * (1.f / 128.f) - mean * mean + 1e-5f);
    float mr = mean * rstd;
    unsigned rstd2 = pkrtz(rstd, rstd);
    unsigned nmr2 = pkrtz(-mr, -mr);

    float dot = 0.f;
#pragma unroll
    for (int c = 0; c < 16; ++c) {
        unsigned base = (unsigned)(((c << 1) + par) * 2);
        uint2 gg = *(const uint2*)&lwh[base];
        uint2 ll = *(const uint2*)&lwh[64 + base];
        uint2 ww = *(const uint2*)&lwh[128 + base];
        unsigned u0 = pk_fma_f16(tp[2 * c], rstd2, nmr2);
        u0 = pk_fma_f16(u0, gg.x, ll.x);
        u0 = pk_max0_f16(u0, zero2);
        dot = fdot2a(u0, ww.x, dot);
        unsigned u1 = pk_fma_f16(tp[2 * c + 1], rstd2, nmr2);
        u1 = pk_fma_f16(u1, gg.y, ll.y);
        u1 = pk_max0_f16(u1, zero2);
        dot = fdot2a(u1, ww.y, dot);
    }
    dot += __shfl_xor(dot, 1, 64);
    if (par == 0) wt[slot] = __expf(dot + ab2[0]);
}

// ---------------- aggregation: 8 lanes/node, 16 ch/lane; sums wt locally ----------------
template <int MODE>
__global__ __launch_bounds__(256) void aggr_kernel(
    const unsigned short* __restrict__ xlbf, const unsigned char* __restrict__ Vf8,
    const float* __restrict__ wt,
    const uint2* __restrict__ er, const int* __restrict__ rowptr,
    const float* __restrict__ g, const float* __restrict__ b,
    void* __restrict__ out, int N) {
    const int lane8 = threadIdx.x & 7;
    const int v = blockIdx.x * 32 + ((int)threadIdx.x >> 3);
    if (v >= N) return;
    const int jb = lane8 * 16;

    const int s0 = rowptr[v], s1e = rowptr[v + 1];
    const int deg = s1e - s0;
    float acc[16];
#pragma unroll
    for (int k = 0; k < 16; ++k) acc[k] = 0.f;
    float wsum = 0.f;

    uint4 v0 = make_uint4(0, 0, 0, 0), v1 = v0;
    float wb0 = 0.f, wb1 = 0.f;
#define GATH2(idx, VV, WW)                                                       \
    if ((idx) < s1e) {                                                           \
        int sn_ = (int)(er[idx].x & 0xFFFFu);                                    \
        VV = *(const uint4*)(Vf8 + (size_t)sn_ * 128 + jb);                      \
        WW = wt[idx];                                                            \
    }
    GATH2(s0, v0, wb0)
    GATH2(s0 + 1, v1, wb1)

    for (int i = s0; i < s1e; i += 2) {
        uint4 c0 = v0, c1 = v1;
        float u0 = wb0;
        float u1 = (i + 1 < s1e) ? wb1 : 0.f;
        GATH2(i + 2, v0, wb0)
        GATH2(i + 3, v1, wb1)
        wsum += u0 + u1;
        unsigned d0[4] = {c0.x, c0.y, c0.z, c0.w};
        unsigned d1[4] = {c1.x, c1.y, c1.z, c1.w};
#pragma unroll
        for (int k = 0; k < 4; ++k) {
            f32x2 alo = __builtin_amdgcn_cvt_pk_f32_fp8((int)d0[k], false);
            f32x2 ahi = __builtin_amdgcn_cvt_pk_f32_fp8((int)d0[k], true);
            f32x2 blo = __builtin_amdgcn_cvt_pk_f32_fp8((int)d1[k], false);
            f32x2 bhi = __builtin_amdgcn_cvt_pk_f32_fp8((int)d1[k], true);
            acc[4 * k + 0] += u0 * alo[0] + u1 * blo[0];
            acc[4 * k + 1] += u0 * alo[1] + u1 * blo[1];
            acc[4 * k + 2] += u0 * ahi[0] + u1 * bhi[0];
            acc[4 * k + 3] += u0 * ahi[1] + u1 * bhi[1];
        }
    }
#undef GATH2

    const float ns = (deg > 0) ? 1.f / (wsum * (float)deg) : 0.f;
    float o[16];
    const unsigned short* xp = xlbf + (size_t)v * 128 + jb;
    uint4 xa = *(const uint4*)xp;
    uint4 xb = *(const uint4*)(xp + 8);
    unsigned xw[8] = {xa.x, xa.y, xa.z, xa.w, xb.x, xb.y, xb.z, xb.w};
#pragma unroll
    for (int k = 0; k < 8; ++k) {
        o[2 * k] = bflo(xw[k]) + acc[2 * k] * ns;
        o[2 * k + 1] = bfhi(xw[k]) + acc[2 * k + 1] * ns;
    }

    if (MODE == 0) {
        unsigned short* op = (unsigned short*)out + (size_t)v * 128 + jb;
        unsigned opk[8];
#pragma unroll
        for (int k = 0; k < 8; ++k)
            opk[k] = (unsigned)f2bf(fmaxf(o[2 * k], 0.f)) |
                     ((unsigned)f2bf(fmaxf(o[2 * k + 1], 0.f)) << 16);
        *(uint4*)op = make_uint4(opk[0], opk[1], opk[2], opk[3]);
        *(uint4*)(op + 8) = make_uint4(opk[4], opk[5], opk[6], opk[7]);
    } else {
        float r1 = 0.f, r2 = 0.f;
#pragma unroll
        for (int k = 0; k < 16; ++k) { r1 += o[k]; r2 = fmaf(o[k], o[k], r2); }
#pragma unroll
        for (int mk = 4; mk >= 1; mk >>= 1) {
            r1 += __shfl_xor(r1, mk, 64);
            r2 += __shfl_xor(r2, mk, 64);
        }
        float mean = r1 * (1.f / 128.f);
        float rstd = rsqrtf(r2 * (1.f / 128.f) - mean * mean + 1e-5f);
        float mr = mean * rstd;
        float* op = (float*)out + (size_t)v * 128 + jb;
#pragma unroll
        for (int k4 = 0; k4 < 4; ++k4) {
            float4 gv = *(const float4*)(g + jb + 4 * k4);
            float4 bv = *(const float4*)(b + jb + 4 * k4);
            float4 r;
            r.x = fmaf(fmaf(o[4 * k4 + 0], rstd, -mr), gv.x, bv.x);
            r.y = fmaf(fmaf(o[4 * k4 + 1], rstd, -mr), gv.y, bv.y);
            r.z = fmaf(fmaf(o[4 * k4 + 2], rstd, -mr), gv.z, bv.z);
            r.w = fmaf(fmaf(o[4 * k4 + 3], rstd, -mr), gv.w, bv.w);
            *(float4*)(op + 4 * k4) = r;
        }
    }
}

// ---------------- pool stage 1: per-(graph, slice) partial max ----------------
__global__ __launch_bounds__(128) void pool1_kernel(const float* __restrict__ h,
                                                    const int* __restrict__ gstart,
                                                    const int* __restrict__ gend,
                                                    float* __restrict__ part) {
    int gph = blockIdx.x >> 4;
    int sl = blockIdx.x & 15;
    int col = threadIdx.x;
    int s = gstart[gph], e = gend[gph];
    float m = -INFINITY;
    for (int r = s + sl; r < e; r += 16) m = fmaxf(m, h[(size_t)r * 128 + col]);
    part[(size_t)blockIdx.x * 128 + col] = m;
}

// ---------------- classifier head (folds pool stage 2) ----------------
__global__ __launch_bounds__(128) void cls_kernel(const float* __restrict__ part,
                                                  const float* __restrict__ cw,
                                                  const float* __restrict__ cb,
                                                  float* __restrict__ out) {
    int gph = blockIdx.x, c = threadIdx.x;
    float m = -INFINITY;
#pragma unroll
    for (int sl = 0; sl < 16; ++sl) m = fmaxf(m, part[(size_t)(gph * 16 + sl) * 128 + c]);
    __shared__ float f[128];
    f[c] = m;
    __syncthreads();
    float acc = cb[c];
#pragma unroll 8
    for (int k = 0; k < 128; ++k) acc += f[k] * cw[k * 128 + c];
    out[gph * 128 + c] = acc;
}

// ---------------- launch ----------------
extern "C" void kernel_launch(void* const* d_in, const int* in_sizes, int n_in,
                              void* d_out, int out_size, void* d_ws, size_t ws_size,
                              hipStream_t stream) {
    const float* x      = (const float*)d_in[0];
    const int*   ei     = (const int*)d_in[1];
    const float* aux    = (const float*)d_in[2];
    const int*   batch  = (const int*)d_in[3];
    const float* w_lin1 = (const float*)d_in[4];
    const float* b_lin1 = (const float*)d_in[5];
    const float* aw1_1  = (const float*)d_in[6];
    const float* ab1_1  = (const float*)d_in[7];
    const float* lng1   = (const float*)d_in[8];
    const float* lnb1   = (const float*)d_in[9];
    const float* aw2_1  = (const float*)d_in[10];
    const float* ab2_1  = (const float*)d_in[11];
    const float* w_lin2 = (const float*)d_in[12];
    const float* b_lin2 = (const float*)d_in[13];
    const float* aw1_2  = (const float*)d_in[14];
    const float* ab1_2  = (const float*)d_in[15];
    const float* lng2   = (const float*)d_in[16];
    const float* lnb2   = (const float*)d_in[17];
    const float* aw2_2  = (const float*)d_in[18];
    const float* ab2_2  = (const float*)d_in[19];
    const float* cls_w  = (const float*)d_in[20];
    const float* cls_b  = (const float*)d_in[21];
    const float* norm_g = (const float*)d_in[22];
    const float* norm_b = (const float*)d_in[23];

    const int N = in_sizes[0] / 128;
    const int E = in_sizes[2] / 2;
    const int G = 64;
    const int* src = ei;
    const int* dst = ei + E;

    // workspace layout: 16B-aligned buffers first
    char* wsp = (char*)d_ws;
    unsigned short* xlbf  = (unsigned short*)wsp;   wsp += (size_t)N * 128 * 2;
    unsigned short* h1bf  = (unsigned short*)wsp;   wsp += (size_t)N * 128 * 2;
    unsigned char*  Pf8   = (unsigned char*)wsp;    wsp += (size_t)N * 128;
    unsigned char*  Qf8   = (unsigned char*)wsp;    wsp += (size_t)N * 128;
    unsigned char*  Vf8   = (unsigned char*)wsp;    wsp += (size_t)N * 128;
    unsigned short* wpack = (unsigned short*)wsp;   wsp += 6 * 16384 * 2;
    float*          part  = (float*)wsp;            wsp += (size_t)1024 * 128 * 4;
    uint2*          er    = (uint2*)wsp;            wsp += (size_t)E * 8;
    float*          wt    = (float*)wsp;            wsp += (size_t)E * 4;
    int*            bsum    = (int*)wsp;            wsp += 256 * 4;
    int*            deg     = (int*)wsp;            wsp += (size_t)N * 4;
    int*            cursor  = (int*)wsp;            wsp += (size_t)N * 4;
    int*            rowptr  = (int*)wsp;            wsp += (size_t)(N + 1) * 4;
    int*            gstart  = (int*)wsp;            wsp += (size_t)G * 4;
    int*            gend    = (int*)wsp;            wsp += (size_t)G * 4;

    unsigned short* wp_lin1 = wpack;
    unsigned short* wp_s1   = wpack + 16384;
    unsigned short* wp_d1   = wpack + 2 * 16384;
    unsigned short* wp_lin2 = wpack + 3 * 16384;
    unsigned short* wp_s2   = wpack + 4 * 16384;
    unsigned short* wp_d2   = wpack + 5 * 16384;

    float* hout   = (float*)d_out;
    float* clsout = hout + (size_t)N * 128;

    hipMemsetAsync(deg, 0, (size_t)(2 * N) * sizeof(int), stream);      // deg + cursor
    hipMemsetAsync(gstart, 0, (size_t)(2 * G) * sizeof(int), stream);

    const int eb = (E + 255) / 256;
    const int nb = (N + 255) / 256;
    const int lb = (N + 31) / 32;
    const int atb = (E + 127) / 128;
    const int agb = (N + 31) / 32;

    prep_kernel<<<384 + eb, 256, 0, stream>>>(w_lin1, aw1_1, aw1_1 + 128 * 128,
                                              w_lin2, aw1_2, aw1_2 + 128 * 128,
                                              wpack, dst, deg, E);
    scan1_kernel<<<nb, 256, 0, stream>>>(deg, rowptr, bsum, N);
    scan23_kernel<<<nb, 256, 0, stream>>>(rowptr, bsum, batch, gstart, gend, N, E);

    // ---- conv1 (scatter overlapped with linpq) ----
    linpq_scat_kernel<<<lb + eb, 256, 0, stream>>>(x, wp_lin1, b_lin1, wp_s1, wp_d1,
                                                   ab1_1, xlbf, Vf8, Pf8, Qf8, N, lb,
                                                   src, dst, aux, rowptr, cursor, er, E);
    attn_edge_kernel<<<atb, 256, 0, stream>>>(Pf8, Qf8, er,
                                              aw1_1 + 256 * 128, aw1_1 + 257 * 128,
                                              lng1, lnb1, aw2_1, ab2_1, wt, E);
    aggr_kernel<0><<<agb, 256, 0, stream>>>(xlbf, Vf8, wt, er, rowptr,
                                            nullptr, nullptr, h1bf, N);
    // ---- conv2 ----
    linpq_kernel<<<lb, 256, 0, stream>>>(h1bf, wp_lin2, b_lin2, wp_s2, wp_d2, ab1_2,
                                         xlbf, Vf8, Pf8, Qf8, N);
    attn_edge_kernel<<<atb, 256, 0, stream>>>(Pf8, Qf8, er,
                                              aw1_2 + 256 * 128, aw1_2 + 257 * 128,
                                              lng2, lnb2, aw2_2, ab2_2, wt, E);
    aggr_kernel<1><<<agb, 256, 0, stream>>>(xlbf, Vf8, wt, er, rowptr,
                                            norm_g, norm_b, hout, N);
    // ---- head ----
    pool1_kernel<<<G * 16, 128, 0, stream>>>(hout, gstart, gend, part);
    cls_kernel<<<G, 128, 0, stream>>>(part, cls_w, cls_b, clsout);
}

// Round 27
// 216.750 us; speedup vs baseline: 1.0611x; 1.0005x over previous
//
#include <hip/hip_runtime.h>
#include <math.h>

typedef __attribute__((ext_vector_type(8))) short short8v;   // 8 bf16 (4 VGPR)
typedef __attribute__((ext_vector_type(4))) float f32x4;
typedef __attribute__((ext_vector_type(2))) float f32x2;

// ---------------- helpers ----------------
__device__ __forceinline__ unsigned short f2bf(float f) {
    union { float f; unsigned int u; } v; v.f = f;
    unsigned int r = v.u + 0x7FFFu + ((v.u >> 16) & 1u);
    return (unsigned short)(r >> 16);
}
__device__ __forceinline__ float bflo(unsigned int v) {
    union { unsigned int u; float f; } x; x.u = v << 16; return x.f;
}
__device__ __forceinline__ float bfhi(unsigned int v) {
    union { unsigned int u; float f; } x; x.u = v & 0xFFFF0000u; return x.f;
}
__device__ __forceinline__ unsigned char f2fp8(float f) {
    return (unsigned char)(__builtin_amdgcn_cvt_pk_fp8_f32(f, f, 0, false) & 0xFF);
}
__device__ __forceinline__ unsigned pkrtz(float a, float b) {
    unsigned d;
    asm("v_cvt_pkrtz_f16_f32 %0, %1, %2" : "=v"(d) : "v"(a), "v"(b));
    return d;
}
__device__ __forceinline__ float fdot2a(unsigned a, unsigned b, float c) {
    float d;
    asm("v_dot2_f32_f16 %0, %1, %2, %3" : "=v"(d) : "v"(a), "v"(b), "v"(c));
    return d;
}
__device__ __forceinline__ unsigned pk_fma_f16(unsigned a, unsigned b, unsigned c) {
    unsigned d;
    asm("v_pk_fma_f16 %0, %1, %2, %3" : "=v"(d) : "v"(a), "v"(b), "v"(c));
    return d;
}
__device__ __forceinline__ unsigned pk_max0_f16(unsigned a, unsigned z) {
    unsigned d;
    asm("v_pk_max_f16 %0, %1, %2" : "=v"(d) : "v"(a), "v"(z));
    return d;
}

// ---------------- prep: weight pack (384 blocks) + dst histogram (rest) ----------------
__global__ __launch_bounds__(256) void prep_kernel(const float* __restrict__ s0,
                                                   const float* __restrict__ s1,
                                                   const float* __restrict__ s2,
                                                   const float* __restrict__ s3,
                                                   const float* __restrict__ s4,
                                                   const float* __restrict__ s5,
                                                   unsigned short* __restrict__ Wp,
                                                   const int* __restrict__ dst,
                                                   int* __restrict__ deg, int E) {
    int b = blockIdx.x;
    if (b < 384) {
        int which = b >> 6;
        const float* W = (which == 0) ? s0 : (which == 1) ? s1 : (which == 2) ? s2
                       : (which == 3) ? s3 : (which == 4) ? s4 : s5;
        int t = (b & 63) * 256 + threadIdx.x;
        int j = t & 7, l = (t >> 3) & 63, ct = (t >> 9) & 7, ks = t >> 12;
        int k = ks * 32 + (l >> 4) * 8 + j;
        int n = ct * 16 + (l & 15);
        Wp[which * 16384 + t] = f2bf(W[k * 128 + n]);
    } else {
        int e = (b - 384) * 256 + threadIdx.x;
        if (e < E) atomicAdd(&deg[dst[e]], 1);
    }
}

// ---------------- scan stage 1 ----------------
__global__ __launch_bounds__(256) void scan1_kernel(const int* __restrict__ deg,
                                                    int* __restrict__ rp,
                                                    int* __restrict__ bsum, int N) {
    const int lane = threadIdx.x & 63, wid = threadIdx.x >> 6;
    int i = blockIdx.x * 256 + threadIdx.x;
    int v = (i < N) ? deg[i] : 0;
    int val = v;
#pragma unroll
    for (int off = 1; off < 64; off <<= 1) {
        int t = __shfl_up(val, off, 64);
        if (lane >= off) val += t;
    }
    __shared__ int ws[4];
    if (lane == 63) ws[wid] = val;
    __syncthreads();
    int pre = 0;
#pragma unroll
    for (int w = 0; w < 4; ++w) pre += (w < wid) ? ws[w] : 0;
    int incl = pre + val;
    if (i < N) rp[i] = incl - v;
    if (threadIdx.x == 255) bsum[blockIdx.x] = incl;
}

// ---------------- scan stage 2+3 + graph bounds, fused ----------------
__global__ __launch_bounds__(256) void scan23_kernel(int* __restrict__ rp,
                                                     const int* __restrict__ bsum,
                                                     const int* __restrict__ batch,
                                                     int* __restrict__ gstart,
                                                     int* __restrict__ gend,
                                                     int N, int E) {
    const int lane = threadIdx.x & 63, wid = threadIdx.x >> 6;
    const int b = blockIdx.x;
    int v = ((int)threadIdx.x < b) ? bsum[threadIdx.x] : 0;
#pragma unroll
    for (int m = 32; m >= 1; m >>= 1) v += __shfl_xor(v, m, 64);
    __shared__ int ws[4];
    if (lane == 0) ws[wid] = v;
    __syncthreads();
    int offset = ws[0] + ws[1] + ws[2] + ws[3];
    int i = b * 256 + threadIdx.x;
    if (i < N) {
        rp[i] += offset;
        int bb = batch[i];
        if (i == 0 || batch[i - 1] != bb) gstart[bb] = i;
        if (i == N - 1 || batch[i + 1] != bb) gend[bb] = i + 1;
    }
    if (b == 0 && threadIdx.x == 0) rp[N] = E;
}

// ---------------- FUSED: scatter (latency-bound) || linpq conv1 (compute-bound) ----------------
__global__ __launch_bounds__(256) void linpq_scat_kernel(
    const float* __restrict__ Av,
    const unsigned short* __restrict__ WpL, const float* __restrict__ bias,
    const unsigned short* __restrict__ WpP, const unsigned short* __restrict__ WpQ,
    const float* __restrict__ ab1,
    unsigned short* __restrict__ Dbf, unsigned char* __restrict__ Vf8,
    unsigned char* __restrict__ Pf8, unsigned char* __restrict__ Qf8, int M, int LB,
    const int* __restrict__ src, const int* __restrict__ dst,
    const float* __restrict__ aux, const int* __restrict__ rowptr,
    int* __restrict__ cursor, uint2* __restrict__ er, int E) {
    __shared__ char smem[32 * 136 * 2 + 32 * 128];   // 12800 B
    unsigned short (*lds)[136] = (unsigned short(*)[136])smem;
    unsigned char (*ldsV)[128] = (unsigned char(*)[128])(smem + 8704);
    unsigned char (*ldsP)[128] = (unsigned char(*)[128])smem;           // aliases lds
    unsigned char (*ldsQ)[128] = (unsigned char(*)[128])(smem + 4096);  // aliases lds

    const int b = blockIdx.x;
    int bi;
    bool isScat;
    if (b < 2 * LB) { isScat = ((b & 1) == 0); bi = b >> 1; }
    else            { isScat = true;           bi = LB + (b - 2 * LB); }

    if (isScat) {
        int e = bi * 256 + (int)threadIdx.x;
        if (e < E) {
            int d = dst[e];
            int pos = rowptr[d] + atomicAdd(&cursor[d], 1);
            float2 a = *(const float2*)(aux + 2 * e);
            uint2 r;
            r.x = (unsigned)src[e] | ((unsigned)d << 16);
            r.y = (unsigned)f2bf(a.x) | ((unsigned)f2bf(a.y) << 16);
            er[pos] = r;
        }
        return;
    }

    const int l = threadIdx.x & 63, w = threadIdx.x >> 6;
    const int tile = w >> 1, ch = w & 1;
    const int rowb = bi * 32;
    const int rowbase = rowb + tile * 16;
    const int r = rowbase + (l & 15);
    const int kc = (l >> 4) * 8;

    short8v afr[4];
    if (r < M) {
        const float* ap = Av + (size_t)r * 128 + kc;
#pragma unroll
        for (int ks = 0; ks < 4; ++ks) {
            float4 x0 = *(const float4*)(ap + ks * 32);
            float4 x1 = *(const float4*)(ap + ks * 32 + 4);
            unsigned short u[8] = {f2bf(x0.x), f2bf(x0.y), f2bf(x0.z), f2bf(x0.w),
                                   f2bf(x1.x), f2bf(x1.y), f2bf(x1.z), f2bf(x1.w)};
            afr[ks] = *(short8v*)u;
        }
    } else {
#pragma unroll
        for (int ks = 0; ks < 4; ++ks)
#pragma unroll
            for (int j = 0; j < 8; ++j) afr[ks][j] = 0;
    }

    f32x4 acc[4];
#pragma unroll
    for (int c = 0; c < 4; ++c)
#pragma unroll
        for (int j = 0; j < 4; ++j) acc[c][j] = 0.f;

    const short8v* wl = (const short8v*)WpL;
#pragma unroll
    for (int ks = 0; ks < 4; ++ks)
#pragma unroll
        for (int c = 0; c < 4; ++c)
            acc[c] = __builtin_amdgcn_mfma_f32_16x16x32_bf16(
                afr[ks], wl[(ks * 8 + ch * 4 + c) * 64 + l], acc[c], 0, 0, 0);

    const int lrb = tile * 16 + (l >> 4) * 4;
#pragma unroll
    for (int c = 0; c < 4; ++c) {
        int col = (ch * 4 + c) * 16 + (l & 15);
        float bv = bias[col];
#pragma unroll
        for (int j = 0; j < 4; ++j) {
            float v = acc[c][j] + bv;
            lds[lrb + j][col] = f2bf(v);
            ldsV[lrb + j][col] = f2fp8(v);
        }
    }
    __syncthreads();

    {
        int r2 = threadIdx.x >> 3, q2 = threadIdx.x & 7;  // 8 thr/row
        if (rowb + r2 < M) {
            *(uint4*)(Dbf + (size_t)(rowb + r2) * 128 + q2 * 16) =
                *(uint4*)&lds[r2][q2 * 16];
            *(uint4*)(Dbf + (size_t)(rowb + r2) * 128 + q2 * 16 + 8) =
                *(uint4*)&lds[r2][q2 * 16 + 8];
            *(uint4*)(Vf8 + (size_t)(rowb + r2) * 128 + q2 * 16) =
                *(uint4*)&ldsV[r2][q2 * 16];
        }
    }

    short8v xfr[4];
#pragma unroll
    for (int ks = 0; ks < 4; ++ks)
        xfr[ks] = *(const short8v*)&lds[tile * 16 + (l & 15)][kc + ks * 32];
    __syncthreads();   // close all reads of lds before aliased P/Q writes

    f32x4 accP[4], accQ[4];
#pragma unroll
    for (int c = 0; c < 4; ++c)
#pragma unroll
        for (int j = 0; j < 4; ++j) { accP[c][j] = 0.f; accQ[c][j] = 0.f; }

    const short8v* wp = (const short8v*)WpP;
    const short8v* wq = (const short8v*)WpQ;
#pragma unroll
    for (int ks = 0; ks < 4; ++ks)
#pragma unroll
        for (int c = 0; c < 4; ++c) {
            accP[c] = __builtin_amdgcn_mfma_f32_16x16x32_bf16(
                xfr[ks], wp[(ks * 8 + ch * 4 + c) * 64 + l], accP[c], 0, 0, 0);
            accQ[c] = __builtin_amdgcn_mfma_f32_16x16x32_bf16(
                xfr[ks], wq[(ks * 8 + ch * 4 + c) * 64 + l], accQ[c], 0, 0, 0);
        }

#pragma unroll
    for (int c = 0; c < 4; ++c) {
        int col = (ch * 4 + c) * 16 + (l & 15);
        float b1v = ab1[col];
#pragma unroll
        for (int j = 0; j < 4; ++j) {
            ldsP[lrb + j][col] = f2fp8(accP[c][j]);
            ldsQ[lrb + j][col] = f2fp8(accQ[c][j] + b1v);
        }
    }
    __syncthreads();
    {
        int r2 = threadIdx.x >> 3, q2 = threadIdx.x & 7;
        if (rowb + r2 < M) {
            *(uint4*)(Pf8 + (size_t)(rowb + r2) * 128 + q2 * 16) =
                *(uint4*)&ldsP[r2][q2 * 16];
            *(uint4*)(Qf8 + (size_t)(rowb + r2) * 128 + q2 * 16) =
                *(uint4*)&ldsQ[r2][q2 * 16];
        }
    }
}

// ---------------- two-phase MFMA GEMM (conv2, bf16 input), same LDS aliasing ----------------
__global__ __launch_bounds__(256) void linpq_kernel(const unsigned short* __restrict__ Av,
                                                    const unsigned short* __restrict__ WpL,
                                                    const float* __restrict__ bias,
                                                    const unsigned short* __restrict__ WpP,
                                                    const unsigned short* __restrict__ WpQ,
                                                    const float* __restrict__ ab1,
                                                    unsigned short* __restrict__ Dbf,
                                                    unsigned char* __restrict__ Vf8,
                                                    unsigned char* __restrict__ Pf8,
                                                    unsigned char* __restrict__ Qf8, int M) {
    __shared__ char smem[32 * 136 * 2 + 32 * 128];   // 12800 B
    unsigned short (*lds)[136] = (unsigned short(*)[136])smem;
    unsigned char (*ldsV)[128] = (unsigned char(*)[128])(smem + 8704);
    unsigned char (*ldsP)[128] = (unsigned char(*)[128])smem;
    unsigned char (*ldsQ)[128] = (unsigned char(*)[128])(smem + 4096);

    const int l = threadIdx.x & 63, w = threadIdx.x >> 6;
    const int tile = w >> 1, ch = w & 1;
    const int rowb = blockIdx.x * 32;
    const int rowbase = rowb + tile * 16;
    const int r = rowbase + (l & 15);
    const int kc = (l >> 4) * 8;

    short8v afr[4];
    if (r < M) {
        const unsigned short* ap = Av + (size_t)r * 128 + kc;
#pragma unroll
        for (int ks = 0; ks < 4; ++ks)
            afr[ks] = *(const short8v*)(ap + ks * 32);
    } else {
#pragma unroll
        for (int ks = 0; ks < 4; ++ks)
#pragma unroll
            for (int j = 0; j < 8; ++j) afr[ks][j] = 0;
    }

    f32x4 acc[4];
#pragma unroll
    for (int c = 0; c < 4; ++c)
#pragma unroll
        for (int j = 0; j < 4; ++j) acc[c][j] = 0.f;

    const short8v* wl = (const short8v*)WpL;
#pragma unroll
    for (int ks = 0; ks < 4; ++ks)
#pragma unroll
        for (int c = 0; c < 4; ++c)
            acc[c] = __builtin_amdgcn_mfma_f32_16x16x32_bf16(
                afr[ks], wl[(ks * 8 + ch * 4 + c) * 64 + l], acc[c], 0, 0, 0);

    const int lrb = tile * 16 + (l >> 4) * 4;
#pragma unroll
    for (int c = 0; c < 4; ++c) {
        int col = (ch * 4 + c) * 16 + (l & 15);
        float bv = bias[col];
#pragma unroll
        for (int j = 0; j < 4; ++j) {
            float v = acc[c][j] + bv;
            lds[lrb + j][col] = f2bf(v);
            ldsV[lrb + j][col] = f2fp8(v);
        }
    }
    __syncthreads();

    {
        int r2 = threadIdx.x >> 3, q2 = threadIdx.x & 7;
        if (rowb + r2 < M) {
            *(uint4*)(Dbf + (size_t)(rowb + r2) * 128 + q2 * 16) =
                *(uint4*)&lds[r2][q2 * 16];
            *(uint4*)(Dbf + (size_t)(rowb + r2) * 128 + q2 * 16 + 8) =
                *(uint4*)&lds[r2][q2 * 16 + 8];
            *(uint4*)(Vf8 + (size_t)(rowb + r2) * 128 + q2 * 16) =
                *(uint4*)&ldsV[r2][q2 * 16];
        }
    }

    short8v xfr[4];
#pragma unroll
    for (int ks = 0; ks < 4; ++ks)
        xfr[ks] = *(const short8v*)&lds[tile * 16 + (l & 15)][kc + ks * 32];
    __syncthreads();   // close all reads of lds before aliased P/Q writes

    f32x4 accP[4], accQ[4];
#pragma unroll
    for (int c = 0; c < 4; ++c)
#pragma unroll
        for (int j = 0; j < 4; ++j) { accP[c][j] = 0.f; accQ[c][j] = 0.f; }

    const short8v* wp = (const short8v*)WpP;
    const short8v* wq = (const short8v*)WpQ;
#pragma unroll
    for (int ks = 0; ks < 4; ++ks)
#pragma unroll
        for (int c = 0; c < 4; ++c) {
            accP[c] = __builtin_amdgcn_mfma_f32_16x16x32_bf16(
                xfr[ks], wp[(ks * 8 + ch * 4 + c) * 64 + l], accP[c], 0, 0, 0);
            accQ[c] = __builtin_amdgcn_mfma_f32_16x16x32_bf16(
                xfr[ks], wq[(ks * 8 + ch * 4 + c) * 64 + l], accQ[c], 0, 0, 0);
        }

#pragma unroll
    for (int c = 0; c < 4; ++c) {
        int col = (ch * 4 + c) * 16 + (l & 15);
        float b1v = ab1[col];
#pragma unroll
        for (int j = 0; j < 4; ++j) {
            ldsP[lrb + j][col] = f2fp8(accP[c][j]);
            ldsQ[lrb + j][col] = f2fp8(accQ[c][j] + b1v);
        }
    }
    __syncthreads();
    {
        int r2 = threadIdx.x >> 3, q2 = threadIdx.x & 7;
        if (rowb + r2 < M) {
            *(uint4*)(Pf8 + (size_t)(rowb + r2) * 128 + q2 * 16) =
                *(uint4*)&ldsP[r2][q2 * 16];
            *(uint4*)(Qf8 + (size_t)(rowb + r2) * 128 + q2 * 16) =
                *(uint4*)&ldsQ[r2][q2 * 16];
        }
    }
}

// ---------------- edge-parallel logits: 2 lanes/edge, 64 ch/lane, packed-f16 math ----------------
__global__ __launch_bounds__(256, 4) void attn_edge_kernel(
    const unsigned char* __restrict__ Pf8, const unsigned char* __restrict__ Qf8,
    const uint2* __restrict__ er,
    const float* __restrict__ wa0, const float* __restrict__ wa1,
    const float* __restrict__ lng, const float* __restrict__ lnb,
    const float* __restrict__ aw2, const float* __restrict__ ab2,
    float* __restrict__ wt, int E) {
    __shared__ float lwf[256];      // [arr:2][c:16][par:2][4] f32 (wa0, wa1)
    __shared__ unsigned lwh[192];   // [arr:3][c:16][par:2][pair:2] f16x2 (lng, lnb, aw2)
    {
        int idx = threadIdx.x;
        int arr = idx >> 7, rem = idx & 127;
        int par = rem >> 6, c = (rem >> 2) & 15, e = rem & 3;
        const float* sp = arr ? wa1 : wa0;
        lwf[(((arr * 16 + c) << 1) + par) * 4 + e] = sp[rem];
        if (idx < 192) {
            int a2 = idx >> 6, rem2 = idx & 63;
            int p2 = rem2 >> 5;
            int c2 = (rem2 >> 1) & 15;
            int pr = rem2 & 1;
            int chn = p2 * 64 + c2 * 4 + pr * 2;
            const float* s2 = (a2 == 0) ? lng : (a2 == 1) ? lnb : aw2;
            lwh[(((a2 * 16 + c2) << 1) + p2) * 2 + pr] = pkrtz(s2[chn], s2[chn + 1]);
        }
    }
    __syncthreads();
    const int slot = blockIdx.x * 128 + ((int)threadIdx.x >> 1);
    if (slot >= E) return;
    const int par = threadIdx.x & 1;
    const unsigned one2 = 0x3C003C00u;
    const unsigned zero2 = 0u;
    const int co = par << 6;

    uint2 ev = er[slot];
    const int sn = (int)(ev.x & 0xFFFFu);
    const int dn = (int)(ev.x >> 16);
    const float ax = bflo(ev.y), ay = bfhi(ev.y);

    const uint4* prow = (const uint4*)(Pf8 + (size_t)sn * 128 + co);
    const uint4* qrow = (const uint4*)(Qf8 + (size_t)dn * 128 + co);

    float r1 = 0.f, r2 = 0.f;
    unsigned tp[32];

#pragma unroll
    for (int g = 0; g < 4; ++g) {
        uint4 pv = prow[g];
        uint4 qv = qrow[g];
        unsigned pwa[4] = {pv.x, pv.y, pv.z, pv.w};
        unsigned qwa[4] = {qv.x, qv.y, qv.z, qv.w};
#pragma unroll
        for (int cc = 0; cc < 4; ++cc) {
            const int c = g * 4 + cc;
            f32x2 plo = __builtin_amdgcn_cvt_pk_f32_fp8((int)pwa[cc], false);
            f32x2 phi = __builtin_amdgcn_cvt_pk_f32_fp8((int)pwa[cc], true);
            f32x2 qlo = __builtin_amdgcn_cvt_pk_f32_fp8((int)qwa[cc], false);
            f32x2 qhi = __builtin_amdgcn_cvt_pk_f32_fp8((int)qwa[cc], true);
            float4 w0v = *(const float4*)&lwf[((c << 1) + par) * 4];
            float4 w1v = *(const float4*)&lwf[(((16 + c) << 1) + par) * 4];
            float t0 = plo[0] + qlo[0] + ax * w0v.x + ay * w1v.x;
            float t1 = plo[1] + qlo[1] + ax * w0v.y + ay * w1v.y;
            float t2 = phi[0] + qhi[0] + ax * w0v.z + ay * w1v.z;
            float t3 = phi[1] + qhi[1] + ax * w0v.w + ay * w1v.w;
            unsigned p0 = pkrtz(t0, t1);
            unsigned p1 = pkrtz(t2, t3);
            tp[2 * c] = p0;
            tp[2 * c + 1] = p1;
            r1 = fdot2a(p0, one2, r1);
            r1 = fdot2a(p1, one2, r1);
            r2 = fdot2a(p0, p0, r2);
            r2 = fdot2a(p1, p1, r2);
        }
    }
    r1 += __shfl_xor(r1, 1, 64);
    r2 += __shfl_xor(r2, 1, 64);
    float mean = r1 * (1.f / 128.f);
    float rstd = rsqrtf(r2 * (1.f / 128.f) - mean * mean + 1e-5f);
    float mr = mean * rstd;
    unsigned rstd2 = pkrtz(rstd, rstd);
    unsigned nmr2 = pkrtz(-mr, -mr);

    float dot = 0.f;
#pragma unroll
    for (int c = 0; c < 16; ++c) {
        unsigned base = (unsigned)(((c << 1) + par) * 2);
        uint2 gg = *(const uint2*)&lwh[base];
        uint2 ll = *(const uint2*)&lwh[64 + base];
        uint2 ww = *(const uint2*)&lwh[128 + base];
        unsigned u0 = pk_fma_f16(tp[2 * c], rstd2, nmr2);
        u0 = pk_fma_f16(u0, gg.x, ll.x);
        u0 = pk_max0_f16(u0, zero2);
        dot = fdot2a(u0, ww.x, dot);
        unsigned u1 = pk_fma_f16(tp[2 * c + 1], rstd2, nmr2);
        u1 = pk_fma_f16(u1, gg.y, ll.y);
        u1 = pk_max0_f16(u1, zero2);
        dot = fdot2a(u1, ww.y, dot);
    }
    dot += __shfl_xor(dot, 1, 64);
    if (par == 0) wt[slot] = __expf(dot + ab2[0]);
}

// ---------------- aggregation: 8 lanes/node, 16 ch/lane; sums wt locally ----------------
template <int MODE>
__global__ __launch_bounds__(256) void aggr_kernel(
    const unsigned short* __restrict__ xlbf, const unsigned char* __restrict__ Vf8,
    const float* __restrict__ wt,
    const uint2* __restrict__ er, const int* __restrict__ rowptr,
    const float* __restrict__ g, const float* __restrict__ b,
    void* __restrict__ out, int N) {
    const int lane8 = threadIdx.x & 7;
    const int v = blockIdx.x * 32 + ((int)threadIdx.x >> 3);
    if (v >= N) return;
    const int jb = lane8 * 16;

    const int s0 = rowptr[v], s1e = rowptr[v + 1];
    const int deg = s1e - s0;
    float acc[16];
#pragma unroll
    for (int k = 0; k < 16; ++k) acc[k] = 0.f;
    float wsum = 0.f;

    uint4 v0 = make_uint4(0, 0, 0, 0), v1 = v0;
    float wb0 = 0.f, wb1 = 0.f;
#define GATH2(idx, VV, WW)                                                       \
    if ((idx) < s1e) {                                                           \
        int sn_ = (int)(er[idx].x & 0xFFFFu);                                    \
        VV = *(const uint4*)(Vf8 + (size_t)sn_ * 128 + jb);                      \
        WW = wt[idx];                                                            \
    }
    GATH2(s0, v0, wb0)
    GATH2(s0 + 1, v1, wb1)

    for (int i = s0; i < s1e; i += 2) {
        uint4 c0 = v0, c1 = v1;
        float u0 = wb0;
        float u1 = (i + 1 < s1e) ? wb1 : 0.f;
        GATH2(i + 2, v0, wb0)
        GATH2(i + 3, v1, wb1)
        wsum += u0 + u1;
        unsigned d0[4] = {c0.x, c0.y, c0.z, c0.w};
        unsigned d1[4] = {c1.x, c1.y, c1.z, c1.w};
#pragma unroll
        for (int k = 0; k < 4; ++k) {
            f32x2 alo = __builtin_amdgcn_cvt_pk_f32_fp8((int)d0[k], false);
            f32x2 ahi = __builtin_amdgcn_cvt_pk_f32_fp8((int)d0[k], true);
            f32x2 blo = __builtin_amdgcn_cvt_pk_f32_fp8((int)d1[k], false);
            f32x2 bhi = __builtin_amdgcn_cvt_pk_f32_fp8((int)d1[k], true);
            acc[4 * k + 0] += u0 * alo[0] + u1 * blo[0];
            acc[4 * k + 1] += u0 * alo[1] + u1 * blo[1];
            acc[4 * k + 2] += u0 * ahi[0] + u1 * bhi[0];
            acc[4 * k + 3] += u0 * ahi[1] + u1 * bhi[1];
        }
    }
#undef GATH2

    const float ns = (deg > 0) ? 1.f / (wsum * (float)deg) : 0.f;
    float o[16];
    const unsigned short* xp = xlbf + (size_t)v * 128 + jb;
    uint4 xa = *(const uint4*)xp;
    uint4 xb = *(const uint4*)(xp + 8);
    unsigned xw[8] = {xa.x, xa.y, xa.z, xa.w, xb.x, xb.y, xb.z, xb.w};
#pragma unroll
    for (int k = 0; k < 8; ++k) {
        o[2 * k] = bflo(xw[k]) + acc[2 * k] * ns;
        o[2 * k + 1] = bfhi(xw[k]) + acc[2 * k + 1] * ns;
    }

    if (MODE == 0) {
        unsigned short* op = (unsigned short*)out + (size_t)v * 128 + jb;
        unsigned opk[8];
#pragma unroll
        for (int k = 0; k < 8; ++k)
            opk[k] = (unsigned)f2bf(fmaxf(o[2 * k], 0.f)) |
                     ((unsigned)f2bf(fmaxf(o[2 * k + 1], 0.f)) << 16);
        *(uint4*)op = make_uint4(opk[0], opk[1], opk[2], opk[3]);
        *(uint4*)(op + 8) = make_uint4(opk[4], opk[5], opk[6], opk[7]);
    } else {
        float r1 = 0.f, r2 = 0.f;
#pragma unroll
        for (int k = 0; k < 16; ++k) { r1 += o[k]; r2 = fmaf(o[k], o[k], r2); }
#pragma unroll
        for (int mk = 4; mk >= 1; mk >>= 1) {
            r1 += __shfl_xor(r1, mk, 64);
            r2 += __shfl_xor(r2, mk, 64);
        }
        float mean = r1 * (1.f / 128.f);
        float rstd = rsqrtf(r2 * (1.f / 128.f) - mean * mean + 1e-5f);
        float mr = mean * rstd;
        float* op = (float*)out + (size_t)v * 128 + jb;
#pragma unroll
        for (int k4 = 0; k4 < 4; ++k4) {
            float4 gv = *(const float4*)(g + jb + 4 * k4);
            float4 bv = *(const float4*)(b + jb + 4 * k4);
            float4 r;
            r.x = fmaf(fmaf(o[4 * k4 + 0], rstd, -mr), gv.x, bv.x);
            r.y = fmaf(fmaf(o[4 * k4 + 1], rstd, -mr), gv.y, bv.y);
            r.z = fmaf(fmaf(o[4 * k4 + 2], rstd, -mr), gv.z, bv.z);
            r.w = fmaf(fmaf(o[4 * k4 + 3], rstd, -mr), gv.w, bv.w);
            *(float4*)(op + 4 * k4) = r;
        }
    }
}

// ---------------- pool stage 1: per-(graph, slice) partial max ----------------
__global__ __launch_bounds__(128) void pool1_kernel(const float* __restrict__ h,
                                                    const int* __restrict__ gstart,
                                                    const int* __restrict__ gend,
                                                    float* __restrict__ part) {
    int gph = blockIdx.x >> 4;
    int sl = blockIdx.x & 15;
    int col = threadIdx.x;
    int s = gstart[gph], e = gend[gph];
    float m = -INFINITY;
    for (int r = s + sl; r < e; r += 16) m = fmaxf(m, h[(size_t)r * 128 + col]);
    part[(size_t)blockIdx.x * 128 + col] = m;
}

// ---------------- classifier head (folds pool stage 2) ----------------
__global__ __launch_bounds__(128) void cls_kernel(const float* __restrict__ part,
                                                  const float* __restrict__ cw,
                                                  const float* __restrict__ cb,
                                                  float* __restrict__ out) {
    int gph = blockIdx.x, c = threadIdx.x;
    float m = -INFINITY;
#pragma unroll
    for (int sl = 0; sl < 16; ++sl) m = fmaxf(m, part[(size_t)(gph * 16 + sl) * 128 + c]);
    __shared__ float f[128];
    f[c] = m;
    __syncthreads();
    float acc = cb[c];
#pragma unroll 8
    for (int k = 0; k < 128; ++k) acc += f[k] * cw[k * 128 + c];
    out[gph * 128 + c] = acc;
}

// ---------------- launch ----------------
extern "C" void kernel_launch(void* const* d_in, const int* in_sizes, int n_in,
                              void* d_out, int out_size, void* d_ws, size_t ws_size,
                              hipStream_t stream) {
    const float* x      = (const float*)d_in[0];
    const int*   ei     = (const int*)d_in[1];
    const float* aux    = (const float*)d_in[2];
    const int*   batch  = (const int*)d_in[3];
    const float* w_lin1 = (const float*)d_in[4];
    const float* b_lin1 = (const float*)d_in[5];
    const float* aw1_1  = (const float*)d_in[6];
    const float* ab1_1  = (const float*)d_in[7];
    const float* lng1   = (const float*)d_in[8];
    const float* lnb1   = (const float*)d_in[9];
    const float* aw2_1  = (const float*)d_in[10];
    const float* ab2_1  = (const float*)d_in[11];
    const float* w_lin2 = (const float*)d_in[12];
    const float* b_lin2 = (const float*)d_in[13];
    const float* aw1_2  = (const float*)d_in[14];
    const float* ab1_2  = (const float*)d_in[15];
    const float* lng2   = (const float*)d_in[16];
    const float* lnb2   = (const float*)d_in[17];
    const float* aw2_2  = (const float*)d_in[18];
    const float* ab2_2  = (const float*)d_in[19];
    const float* cls_w  = (const float*)d_in[20];
    const float* cls_b  = (const float*)d_in[21];
    const float* norm_g = (const float*)d_in[22];
    const float* norm_b = (const float*)d_in[23];

    const int N = in_sizes[0] / 128;
    const int E = in_sizes[2] / 2;
    const int G = 64;
    const int* src = ei;
    const int* dst = ei + E;

    // workspace layout: 16B-aligned buffers first
    char* wsp = (char*)d_ws;
    unsigned short* xlbf  = (unsigned short*)wsp;   wsp += (size_t)N * 128 * 2;
    unsigned short* h1bf  = (unsigned short*)wsp;   wsp += (size_t)N * 128 * 2;
    unsigned char*  Pf8   = (unsigned char*)wsp;    wsp += (size_t)N * 128;
    unsigned char*  Qf8   = (unsigned char*)wsp;    wsp += (size_t)N * 128;
    unsigned char*  Vf8   = (unsigned char*)wsp;    wsp += (size_t)N * 128;
    unsigned short* wpack = (unsigned short*)wsp;   wsp += 6 * 16384 * 2;
    float*          part  = (float*)wsp;            wsp += (size_t)1024 * 128 * 4;
    uint2*          er    = (uint2*)wsp;            wsp += (size_t)E * 8;
    float*          wt    = (float*)wsp;            wsp += (size_t)E * 4;
    int*            bsum    = (int*)wsp;            wsp += 256 * 4;
    int*            deg     = (int*)wsp;            wsp += (size_t)N * 4;
    int*            cursor  = (int*)wsp;            wsp += (size_t)N * 4;
    int*            rowptr  = (int*)wsp;            wsp += (size_t)(N + 1) * 4;
    int*            gstart  = (int*)wsp;            wsp += (size_t)G * 4;
    int*            gend    = (int*)wsp;            wsp += (size_t)G * 4;

    unsigned short* wp_lin1 = wpack;
    unsigned short* wp_s1   = wpack + 16384;
    unsigned short* wp_d1   = wpack + 2 * 16384;
    unsigned short* wp_lin2 = wpack + 3 * 16384;
    unsigned short* wp_s2   = wpack + 4 * 16384;
    unsigned short* wp_d2   = wpack + 5 * 16384;

    float* hout   = (float*)d_out;
    float* clsout = hout + (size_t)N * 128;

    hipMemsetAsync(deg, 0, (size_t)(2 * N) * sizeof(int), stream);      // deg + cursor
    hipMemsetAsync(gstart, 0, (size_t)(2 * G) * sizeof(int), stream);

    const int eb = (E + 255) / 256;
    const int nb = (N + 255) / 256;
    const int lb = (N + 31) / 32;
    const int atb = (E + 127) / 128;
    const int agb = (N + 31) / 32;

    prep_kernel<<<384 + eb, 256, 0, stream>>>(w_lin1, aw1_1, aw1_1 + 128 * 128,
                                              w_lin2, aw1_2, aw1_2 + 128 * 128,
                                              wpack, dst, deg, E);
    scan1_kernel<<<nb, 256, 0, stream>>>(deg, rowptr, bsum, N);
    scan23_kernel<<<nb, 256, 0, stream>>>(rowptr, bsum, batch, gstart, gend, N, E);

    // ---- conv1 (scatter overlapped with linpq) ----
    linpq_scat_kernel<<<lb + eb, 256, 0, stream>>>(x, wp_lin1, b_lin1, wp_s1, wp_d1,
                                                   ab1_1, xlbf, Vf8, Pf8, Qf8, N, lb,
                                                   src, dst, aux, rowptr, cursor, er, E);
    attn_edge_kernel<<<atb, 256, 0, stream>>>(Pf8, Qf8, er,
                                              aw1_1 + 256 * 128, aw1_1 + 257 * 128,
                                              lng1, lnb1, aw2_1, ab2_1, wt, E);
    aggr_kernel<0><<<agb, 256, 0, stream>>>(xlbf, Vf8, wt, er, rowptr,
                                            nullptr, nullptr, h1bf, N);
    // ---- conv2 ----
    linpq_kernel<<<lb, 256, 0, stream>>>(h1bf, wp_lin2, b_lin2, wp_s2, wp_d2, ab1_2,
                                         xlbf, Vf8, Pf8, Qf8, N);
    attn_edge_kernel<<<atb, 256, 0, stream>>>(Pf8, Qf8, er,
                                              aw1_2 + 256 * 128, aw1_2 + 257 * 128,
                                              lng2, lnb2, aw2_2, ab2_2, wt, E);
    aggr_kernel<1><<<agb, 256, 0, stream>>>(xlbf, Vf8, wt, er, rowptr,
                                            norm_g, norm_b, hout, N);
    // ---- head ----
    pool1_kernel<<<G * 16, 128, 0, stream>>>(hout, gstart, gend, part);
    cls_kernel<<<G, 128, 0, stream>>>(part, cls_w, cls_b, clsout);
}